// Round 1
// baseline (3102.652 us; speedup 1.0000x reference)
//
#include <hip/hip_runtime.h>
#include <hip/hip_bf16.h>

// ---------------------------------------------------------------------------
// GAT 3-layer forward. f32 everywhere (round 0: correctness + baseline).
// Layers 1,2: 8 heads x 64 ch, concat + ELU. Layer 3: 1 head x 3 ch.
// Segment softmax via exact atomicMax on monotone uint keys.
// ---------------------------------------------------------------------------

#define HEADS 8
#define HID 64
#define F512 512

__device__ __forceinline__ unsigned fkey(float f) {
    unsigned b = __float_as_uint(f);
    return (b & 0x80000000u) ? ~b : (b | 0x80000000u);
}
__device__ __forceinline__ float keyf(unsigned k) {
    return (k & 0x80000000u) ? __uint_as_float(k & 0x7FFFFFFFu) : __uint_as_float(~k);
}

// h[n][j] = sum_{k<12} x[n][k] * W1[k][j]   (j in 0..511)
__global__ void gemm1_kernel(const float* __restrict__ x, const float* __restrict__ W1,
                             float* __restrict__ h, int N) {
    int idx = blockIdx.x * blockDim.x + threadIdx.x;
    if (idx >= N * F512) return;
    int n = idx >> 9, j = idx & 511;
    const float* xr = x + (size_t)n * 12;
    float acc = 0.f;
#pragma unroll
    for (int k = 0; k < 12; ++k) acc += xr[k] * W1[k * F512 + j];
    h[idx] = acc;
}

// Tiled f32 GEMM: C[M,Nn] = A[M,K] @ B[K,Nn]. BM=BN=64, BK=16, 256 thr, 4x4 micro.
__global__ __launch_bounds__(256) void gemm_tiled(const float* __restrict__ A,
                                                  const float* __restrict__ B,
                                                  float* __restrict__ C,
                                                  int M, int Nn, int K) {
    __shared__ float As[16][65];
    __shared__ float Bs[16][64];
    int t = threadIdx.x;
    int tx = t & 15, ty = t >> 4;
    int rowBase = blockIdx.y * 64;
    int colBase = blockIdx.x * 64;
    float acc[4][4] = {};
    int am = t >> 2;          // 0..63
    int ak = (t & 3) * 4;     // 0,4,8,12
    int bk = t >> 4;          // 0..15
    int bn = (t & 15) * 4;    // 0..60
    for (int k0 = 0; k0 < K; k0 += 16) {
        int arow = rowBase + am;
        float4 av = make_float4(0.f, 0.f, 0.f, 0.f);
        if (arow < M) av = *(const float4*)(A + (size_t)arow * K + k0 + ak);
        As[ak + 0][am] = av.x; As[ak + 1][am] = av.y;
        As[ak + 2][am] = av.z; As[ak + 3][am] = av.w;
        float4 bv = *(const float4*)(B + (size_t)(k0 + bk) * Nn + colBase + bn);
        *(float4*)&Bs[bk][bn] = bv;
        __syncthreads();
#pragma unroll
        for (int k = 0; k < 16; ++k) {
            float a0 = As[k][ty * 4 + 0], a1 = As[k][ty * 4 + 1];
            float a2 = As[k][ty * 4 + 2], a3 = As[k][ty * 4 + 3];
            float b0 = Bs[k][tx * 4 + 0], b1 = Bs[k][tx * 4 + 1];
            float b2 = Bs[k][tx * 4 + 2], b3 = Bs[k][tx * 4 + 3];
            acc[0][0] += a0 * b0; acc[0][1] += a0 * b1; acc[0][2] += a0 * b2; acc[0][3] += a0 * b3;
            acc[1][0] += a1 * b0; acc[1][1] += a1 * b1; acc[1][2] += a1 * b2; acc[1][3] += a1 * b3;
            acc[2][0] += a2 * b0; acc[2][1] += a2 * b1; acc[2][2] += a2 * b2; acc[2][3] += a2 * b3;
            acc[3][0] += a3 * b0; acc[3][1] += a3 * b1; acc[3][2] += a3 * b2; acc[3][3] += a3 * b3;
        }
        __syncthreads();
    }
#pragma unroll
    for (int i = 0; i < 4; ++i) {
        int row = rowBase + ty * 4 + i;
        if (row < M) {
            float4 v = make_float4(acc[i][0], acc[i][1], acc[i][2], acc[i][3]);
            *(float4*)(C + (size_t)row * Nn + colBase + tx * 4) = v;
        }
    }
}

// alpha_src/dst per (node, head): wave per node, lane = channel.
__global__ void alpha8_kernel(const float* __restrict__ h, const float* __restrict__ asrc,
                              const float* __restrict__ adst, float* __restrict__ a_s,
                              float* __restrict__ a_d, int N) {
    int wave = (blockIdx.x * blockDim.x + threadIdx.x) >> 6;
    int lane = threadIdx.x & 63;
    if (wave >= N) return;
#pragma unroll
    for (int hh = 0; hh < HEADS; ++hh) {
        float v = h[(size_t)wave * F512 + hh * HID + lane];
        float s = v * asrc[hh * HID + lane];
        float d = v * adst[hh * HID + lane];
        for (int off = 32; off; off >>= 1) {
            s += __shfl_down(s, off);
            d += __shfl_down(d, off);
        }
        if (lane == 0) {
            a_s[wave * HEADS + hh] = s;
            a_d[wave * HEADS + hh] = d;
        }
    }
}

template <int H>
__global__ void edge_max_kernel(const int* __restrict__ src, const int* __restrict__ dst,
                                int E, int N, const float* __restrict__ as,
                                const float* __restrict__ ad, unsigned* __restrict__ emax) {
    int tid = blockIdx.x * blockDim.x + threadIdx.x;
    int total = (E + N) * H;
    if (tid >= total) return;
    int e = tid / H, hh = tid - e * H;
    int s, d;
    if (e < E) { s = src[e]; d = dst[e]; } else { s = d = e - E; }
    float v = as[s * H + hh] + ad[d * H + hh];
    v = v >= 0.f ? v : 0.2f * v;
    atomicMax(&emax[d * H + hh], fkey(v));
}

template <int H>
__global__ void edge_sum_kernel(const int* __restrict__ src, const int* __restrict__ dst,
                                int E, int N, const float* __restrict__ as,
                                const float* __restrict__ ad, const unsigned* __restrict__ emax,
                                float* __restrict__ denom) {
    int tid = blockIdx.x * blockDim.x + threadIdx.x;
    int total = (E + N) * H;
    if (tid >= total) return;
    int e = tid / H, hh = tid - e * H;
    int s, d;
    if (e < E) { s = src[e]; d = dst[e]; } else { s = d = e - E; }
    float v = as[s * H + hh] + ad[d * H + hh];
    v = v >= 0.f ? v : 0.2f * v;
    float ex = expf(v - keyf(emax[d * H + hh]));
    atomicAdd(&denom[d * H + hh], ex);
}

// Aggregation, layers 1/2: wave per edge, lane = channel, loop heads.
__global__ void edge_aggr8_kernel(const int* __restrict__ src, const int* __restrict__ dst,
                                  int E, int N, const float* __restrict__ as,
                                  const float* __restrict__ ad, const unsigned* __restrict__ emax,
                                  const float* __restrict__ denom, const float* __restrict__ h,
                                  float* __restrict__ out) {
    int wave = (blockIdx.x * blockDim.x + threadIdx.x) >> 6;
    int lane = threadIdx.x & 63;
    int Etot = E + N;
    if (wave >= Etot) return;
    int s, d;
    if (wave < E) { s = src[wave]; d = dst[wave]; } else { s = d = wave - E; }
#pragma unroll
    for (int hh = 0; hh < HEADS; ++hh) {
        float v = as[s * HEADS + hh] + ad[d * HEADS + hh];
        v = v >= 0.f ? v : 0.2f * v;
        float ex = expf(v - keyf(emax[d * HEADS + hh]));
        float alpha = ex / (denom[d * HEADS + hh] + 1e-16f);
        float m = h[(size_t)s * F512 + hh * HID + lane] * alpha;
        atomicAdd(&out[(size_t)d * F512 + hh * HID + lane], m);
    }
}

__global__ void bias_elu_kernel(float* __restrict__ h, const float* __restrict__ b, size_t total) {
    size_t idx = (size_t)blockIdx.x * blockDim.x + threadIdx.x;
    if (idx >= total) return;
    float v = h[idx] + b[idx & 511];
    h[idx] = v > 0.f ? v : expm1f(v);
}

// Layer 3: h3[n,0..2] = h[n,:] @ W3, wave per node.
__global__ void gemm3_kernel(const float* __restrict__ h, const float* __restrict__ W3,
                             float* __restrict__ h3, int N) {
    int wave = (blockIdx.x * blockDim.x + threadIdx.x) >> 6;
    int lane = threadIdx.x & 63;
    if (wave >= N) return;
    float a0 = 0.f, a1 = 0.f, a2 = 0.f;
    for (int k = lane; k < F512; k += 64) {
        float v = h[(size_t)wave * F512 + k];
        a0 += v * W3[k * 3 + 0];
        a1 += v * W3[k * 3 + 1];
        a2 += v * W3[k * 3 + 2];
    }
    for (int off = 32; off; off >>= 1) {
        a0 += __shfl_down(a0, off);
        a1 += __shfl_down(a1, off);
        a2 += __shfl_down(a2, off);
    }
    if (lane == 0) {
        h3[(size_t)wave * 3 + 0] = a0;
        h3[(size_t)wave * 3 + 1] = a1;
        h3[(size_t)wave * 3 + 2] = a2;
    }
}

__global__ void alpha3_kernel(const float* __restrict__ h3, const float* __restrict__ asrc,
                              const float* __restrict__ adst, float* __restrict__ a_s,
                              float* __restrict__ a_d, int N) {
    int n = blockIdx.x * blockDim.x + threadIdx.x;
    if (n >= N) return;
    float s = 0.f, d = 0.f;
#pragma unroll
    for (int j = 0; j < 3; ++j) {
        float v = h3[(size_t)n * 3 + j];
        s += v * asrc[j];
        d += v * adst[j];
    }
    a_s[n] = s;
    a_d[n] = d;
}

__global__ void edge_aggr3_kernel(const int* __restrict__ src, const int* __restrict__ dst,
                                  int E, int N, const float* __restrict__ as,
                                  const float* __restrict__ ad, const unsigned* __restrict__ emax,
                                  const float* __restrict__ denom, const float* __restrict__ h3,
                                  float* __restrict__ out) {
    int e = blockIdx.x * blockDim.x + threadIdx.x;
    int Etot = E + N;
    if (e >= Etot) return;
    int s, d;
    if (e < E) { s = src[e]; d = dst[e]; } else { s = d = e - E; }
    float v = as[s] + ad[d];
    v = v >= 0.f ? v : 0.2f * v;
    float ex = expf(v - keyf(emax[d]));
    float alpha = ex / (denom[d] + 1e-16f);
#pragma unroll
    for (int j = 0; j < 3; ++j)
        atomicAdd(&out[(size_t)d * 3 + j], h3[(size_t)s * 3 + j] * alpha);
}

__global__ void bias3_kernel(float* __restrict__ out, const float* __restrict__ b3, int N) {
    int idx = blockIdx.x * blockDim.x + threadIdx.x;
    if (idx >= N * 3) return;
    out[idx] += b3[idx % 3];
}

static inline int cdiv(long long a, long long b) { return (int)((a + b - 1) / b); }

extern "C" void kernel_launch(void* const* d_in, const int* in_sizes, int n_in,
                              void* d_out, int out_size, void* d_ws, size_t ws_size,
                              hipStream_t stream) {
    const int N = in_sizes[0] / 12;
    const int E = in_sizes[1] / 2;
    const float* x     = (const float*)d_in[0];
    const int*   ei    = (const int*)d_in[1];
    const float* W1    = (const float*)d_in[2];
    const float* asrc1 = (const float*)d_in[3];
    const float* adst1 = (const float*)d_in[4];
    const float* b1    = (const float*)d_in[5];
    const float* W2    = (const float*)d_in[6];
    const float* asrc2 = (const float*)d_in[7];
    const float* adst2 = (const float*)d_in[8];
    const float* b2    = (const float*)d_in[9];
    const float* W3    = (const float*)d_in[10];
    const float* asrc3 = (const float*)d_in[11];
    const float* adst3 = (const float*)d_in[12];
    const float* b3    = (const float*)d_in[13];

    const int* srcv = ei;
    const int* dstv = ei + E;
    float* out = (float*)d_out;

    char* ws = (char*)d_ws;
    size_t szH = (size_t)N * F512 * sizeof(float);
    float*    hA    = (float*)ws;
    float*    hB    = (float*)(ws + szH);
    float*    a_s   = (float*)(ws + 2 * szH);
    float*    a_d   = a_s + (size_t)N * HEADS;
    unsigned* emax  = (unsigned*)(a_d + (size_t)N * HEADS);
    float*    denom = (float*)(emax + (size_t)N * HEADS);
    float*    h3    = denom + (size_t)N * HEADS;

    const int Etot = E + N;
    const size_t totH = (size_t)N * F512;

    // ----------------- Layer 1 -----------------
    gemm1_kernel<<<cdiv(totH, 256), 256, 0, stream>>>(x, W1, hA, N);
    alpha8_kernel<<<cdiv((long long)N * 64, 256), 256, 0, stream>>>(hA, asrc1, adst1, a_s, a_d, N);
    hipMemsetAsync(emax, 0, (size_t)N * HEADS * 4, stream);
    hipMemsetAsync(denom, 0, (size_t)N * HEADS * 4, stream);
    edge_max_kernel<HEADS><<<cdiv((long long)Etot * HEADS, 256), 256, 0, stream>>>(srcv, dstv, E, N, a_s, a_d, emax);
    edge_sum_kernel<HEADS><<<cdiv((long long)Etot * HEADS, 256), 256, 0, stream>>>(srcv, dstv, E, N, a_s, a_d, emax, denom);
    hipMemsetAsync(hB, 0, szH, stream);
    edge_aggr8_kernel<<<cdiv((long long)Etot * 64, 256), 256, 0, stream>>>(srcv, dstv, E, N, a_s, a_d, emax, denom, hA, hB);
    bias_elu_kernel<<<cdiv(totH, 256), 256, 0, stream>>>(hB, b1, totH);

    // ----------------- Layer 2 -----------------
    {
        dim3 grid(F512 / 64, cdiv(N, 64));
        gemm_tiled<<<grid, 256, 0, stream>>>(hB, W2, hA, N, F512, F512);
    }
    alpha8_kernel<<<cdiv((long long)N * 64, 256), 256, 0, stream>>>(hA, asrc2, adst2, a_s, a_d, N);
    hipMemsetAsync(emax, 0, (size_t)N * HEADS * 4, stream);
    hipMemsetAsync(denom, 0, (size_t)N * HEADS * 4, stream);
    edge_max_kernel<HEADS><<<cdiv((long long)Etot * HEADS, 256), 256, 0, stream>>>(srcv, dstv, E, N, a_s, a_d, emax);
    edge_sum_kernel<HEADS><<<cdiv((long long)Etot * HEADS, 256), 256, 0, stream>>>(srcv, dstv, E, N, a_s, a_d, emax, denom);
    hipMemsetAsync(hB, 0, szH, stream);
    edge_aggr8_kernel<<<cdiv((long long)Etot * 64, 256), 256, 0, stream>>>(srcv, dstv, E, N, a_s, a_d, emax, denom, hA, hB);
    bias_elu_kernel<<<cdiv(totH, 256), 256, 0, stream>>>(hB, b2, totH);

    // ----------------- Layer 3 -----------------
    gemm3_kernel<<<cdiv((long long)N * 64, 256), 256, 0, stream>>>(hB, W3, h3, N);
    alpha3_kernel<<<cdiv(N, 256), 256, 0, stream>>>(h3, asrc3, adst3, a_s, a_d, N);
    hipMemsetAsync(emax, 0, (size_t)N * 4, stream);
    hipMemsetAsync(denom, 0, (size_t)N * 4, stream);
    edge_max_kernel<1><<<cdiv(Etot, 256), 256, 0, stream>>>(srcv, dstv, E, N, a_s, a_d, emax);
    edge_sum_kernel<1><<<cdiv(Etot, 256), 256, 0, stream>>>(srcv, dstv, E, N, a_s, a_d, emax, denom);
    hipMemsetAsync(out, 0, (size_t)N * 3 * 4, stream);
    edge_aggr3_kernel<<<cdiv(Etot, 256), 256, 0, stream>>>(srcv, dstv, E, N, a_s, a_d, emax, denom, h3, out);
    bias3_kernel<<<cdiv((long long)N * 3, 256), 256, 0, stream>>>(out, b3, N);
}

// Round 2
// 1141.985 us; speedup vs baseline: 2.7169x; 2.7169x over previous
//
#include <hip/hip_runtime.h>
#include <hip/hip_bf16.h>

// ---------------------------------------------------------------------------
// GAT 3-layer forward, round 2: CSR-based fused aggregation (no atomics).
// Layers 1,2: 8 heads x 64 ch, concat + ELU. Layer 3: 1 head x 3 ch.
// ---------------------------------------------------------------------------

#define HEADS 8
#define HID 64
#define F512 512

// ---------------- GEMMs ----------------

// h[n][j] = sum_{k<12} x[n][k] * W1[k][j]
__global__ void gemm1_kernel(const float* __restrict__ x, const float* __restrict__ W1,
                             float* __restrict__ h, int N) {
    int idx = blockIdx.x * blockDim.x + threadIdx.x;
    if (idx >= N * F512) return;
    int n = idx >> 9, j = idx & 511;
    const float* xr = x + (size_t)n * 12;
    float acc = 0.f;
#pragma unroll
    for (int k = 0; k < 12; ++k) acc += xr[k] * W1[k * F512 + j];
    h[idx] = acc;
}

// Tiled f32 GEMM: C[M,Nn] = A[M,K] @ B[K,Nn]. BM=BN=64, BK=16, 256 thr, 4x4 micro.
__global__ __launch_bounds__(256) void gemm_tiled(const float* __restrict__ A,
                                                  const float* __restrict__ B,
                                                  float* __restrict__ C,
                                                  int M, int Nn, int K) {
    __shared__ float As[16][65];
    __shared__ float Bs[16][64];
    int t = threadIdx.x;
    int tx = t & 15, ty = t >> 4;
    int rowBase = blockIdx.y * 64;
    int colBase = blockIdx.x * 64;
    float acc[4][4] = {};
    int am = t >> 2;
    int ak = (t & 3) * 4;
    int bk = t >> 4;
    int bn = (t & 15) * 4;
    for (int k0 = 0; k0 < K; k0 += 16) {
        int arow = rowBase + am;
        float4 av = make_float4(0.f, 0.f, 0.f, 0.f);
        if (arow < M) av = *(const float4*)(A + (size_t)arow * K + k0 + ak);
        As[ak + 0][am] = av.x; As[ak + 1][am] = av.y;
        As[ak + 2][am] = av.z; As[ak + 3][am] = av.w;
        float4 bv = *(const float4*)(B + (size_t)(k0 + bk) * Nn + colBase + bn);
        *(float4*)&Bs[bk][bn] = bv;
        __syncthreads();
#pragma unroll
        for (int k = 0; k < 16; ++k) {
            float a0 = As[k][ty * 4 + 0], a1 = As[k][ty * 4 + 1];
            float a2 = As[k][ty * 4 + 2], a3 = As[k][ty * 4 + 3];
            float b0 = Bs[k][tx * 4 + 0], b1 = Bs[k][tx * 4 + 1];
            float b2 = Bs[k][tx * 4 + 2], b3 = Bs[k][tx * 4 + 3];
            acc[0][0] += a0 * b0; acc[0][1] += a0 * b1; acc[0][2] += a0 * b2; acc[0][3] += a0 * b3;
            acc[1][0] += a1 * b0; acc[1][1] += a1 * b1; acc[1][2] += a1 * b2; acc[1][3] += a1 * b3;
            acc[2][0] += a2 * b0; acc[2][1] += a2 * b1; acc[2][2] += a2 * b2; acc[2][3] += a2 * b3;
            acc[3][0] += a3 * b0; acc[3][1] += a3 * b1; acc[3][2] += a3 * b2; acc[3][3] += a3 * b3;
        }
        __syncthreads();
    }
#pragma unroll
    for (int i = 0; i < 4; ++i) {
        int row = rowBase + ty * 4 + i;
        if (row < M) {
            float4 v = make_float4(acc[i][0], acc[i][1], acc[i][2], acc[i][3]);
            *(float4*)(C + (size_t)row * Nn + colBase + tx * 4) = v;
        }
    }
}

// Layer 3 projection: h3[n,0..2] = h[n,:] @ W3, wave per node.
__global__ void gemm3_kernel(const float* __restrict__ h, const float* __restrict__ W3,
                             float* __restrict__ h3, int N) {
    int wave = (blockIdx.x * blockDim.x + threadIdx.x) >> 6;
    int lane = threadIdx.x & 63;
    if (wave >= N) return;
    float a0 = 0.f, a1 = 0.f, a2 = 0.f;
    for (int k = lane; k < F512; k += 64) {
        float v = h[(size_t)wave * F512 + k];
        a0 += v * W3[k * 3 + 0];
        a1 += v * W3[k * 3 + 1];
        a2 += v * W3[k * 3 + 2];
    }
    for (int off = 32; off; off >>= 1) {
        a0 += __shfl_down(a0, off);
        a1 += __shfl_down(a1, off);
        a2 += __shfl_down(a2, off);
    }
    if (lane == 0) {
        h3[(size_t)wave * 3 + 0] = a0;
        h3[(size_t)wave * 3 + 1] = a1;
        h3[(size_t)wave * 3 + 2] = a2;
    }
}

// ---------------- alpha coefficients ----------------

__global__ void alpha8_kernel(const float* __restrict__ h, const float* __restrict__ asrc,
                              const float* __restrict__ adst, float* __restrict__ a_s,
                              float* __restrict__ a_d, int N) {
    int wave = (blockIdx.x * blockDim.x + threadIdx.x) >> 6;
    int lane = threadIdx.x & 63;
    if (wave >= N) return;
#pragma unroll
    for (int hh = 0; hh < HEADS; ++hh) {
        float v = h[(size_t)wave * F512 + hh * HID + lane];
        float s = v * asrc[hh * HID + lane];
        float d = v * adst[hh * HID + lane];
        for (int off = 32; off; off >>= 1) {
            s += __shfl_down(s, off);
            d += __shfl_down(d, off);
        }
        if (lane == 0) {
            a_s[wave * HEADS + hh] = s;
            a_d[wave * HEADS + hh] = d;
        }
    }
}

__global__ void alpha3_kernel(const float* __restrict__ h3, const float* __restrict__ asrc,
                              const float* __restrict__ adst, float* __restrict__ a_s,
                              float* __restrict__ a_d, int N) {
    int n = blockIdx.x * blockDim.x + threadIdx.x;
    if (n >= N) return;
    float s = 0.f, d = 0.f;
#pragma unroll
    for (int j = 0; j < 3; ++j) {
        float v = h3[(size_t)n * 3 + j];
        s += v * asrc[j];
        d += v * adst[j];
    }
    a_s[n] = s;
    a_d[n] = d;
}

// ---------------- CSR build (per launch; deterministic work) ----------------

__global__ void hist_kernel(const int* __restrict__ dst, int E, int* __restrict__ cnt) {
    int e = blockIdx.x * blockDim.x + threadIdx.x;
    if (e < E) atomicAdd(&cnt[dst[e]], 1);
}

__global__ __launch_bounds__(1024) void scan_block_kernel(const int* __restrict__ cnt,
                                                          int* __restrict__ excl,
                                                          int* __restrict__ bsum, int n) {
    __shared__ int s[1024];
    int i = blockIdx.x * 1024 + threadIdx.x;
    int v = i < n ? cnt[i] : 0;
    s[threadIdx.x] = v;
    __syncthreads();
    for (int off = 1; off < 1024; off <<= 1) {
        int t = threadIdx.x >= off ? s[threadIdx.x - off] : 0;
        __syncthreads();
        s[threadIdx.x] += t;
        __syncthreads();
    }
    if (i < n) excl[i] = s[threadIdx.x] - v;
    if (threadIdx.x == 1023) bsum[blockIdx.x] = s[1023];
}

__global__ void scan_aux_kernel(int* __restrict__ bsum, int nb) {
    if (blockIdx.x == 0 && threadIdx.x == 0) {
        int acc = 0;
        for (int i = 0; i < nb; ++i) { int v = bsum[i]; bsum[i] = acc; acc += v; }
    }
}

__global__ void scan_add_kernel(const int* __restrict__ excl, const int* __restrict__ bsum,
                                int* __restrict__ rowptr, int* __restrict__ fill, int n, int E) {
    int i = blockIdx.x * blockDim.x + threadIdx.x;
    if (i < n) {
        int v = excl[i] + bsum[i >> 10];
        rowptr[i] = v;
        fill[i] = v;
    }
    if (i == 0) rowptr[n] = E;
}

__global__ void scatter_kernel(const int* __restrict__ src, const int* __restrict__ dst, int E,
                               int* __restrict__ fill, int* __restrict__ csrc) {
    int e = blockIdx.x * blockDim.x + threadIdx.x;
    if (e >= E) return;
    int pos = atomicAdd(&fill[dst[e]], 1);
    csrc[pos] = src[e];
}

// ---------------- fused segment-softmax + aggregation ----------------
// One 256-thread block per destination node. Implicit self-loop (i == deg).
// out[d] = (sum_e exp(v_e - max) * h[src_e]) / (sum_e exp(v_e - max)) + bias [, ELU]

template <bool ELU>
__global__ __launch_bounds__(256) void gat_aggr_fused(
    const int* __restrict__ rowptr, const int* __restrict__ csrc,
    const float* __restrict__ a_s, const float* __restrict__ a_d,
    const float* __restrict__ h, const float* __restrict__ bias,
    float* __restrict__ out, int N) {
    const int CHUNK = 64;
    __shared__ float smax[HEADS], sden[HEADS], sad[HEADS];
    __shared__ float sex[CHUNK][HEADS];
    __shared__ int ssrc[CHUNK];

    int d = blockIdx.x;
    int tid = threadIdx.x;
    int beg = rowptr[d];
    int deg = rowptr[d + 1] - beg;  // real edges; +1 implicit self edge (i==deg)

    if (tid < HEADS) { sad[tid] = a_d[d * HEADS + tid]; sden[tid] = 0.f; }
    __syncthreads();

    // phase A: per-head max (threads 0..63: head = tid&7, edge stride 8)
    if (tid < 64) {
        int hh = tid & 7;
        float m = -INFINITY;
        for (int i = tid >> 3; i <= deg; i += 8) {
            int s = (i == deg) ? d : csrc[beg + i];
            float v = a_s[s * HEADS + hh] + sad[hh];
            v = v >= 0.f ? v : 0.2f * v;
            m = fmaxf(m, v);
        }
        m = fmaxf(m, __shfl_xor(m, 8));
        m = fmaxf(m, __shfl_xor(m, 16));
        m = fmaxf(m, __shfl_xor(m, 32));
        if (tid < 8) smax[tid] = m;
    }
    __syncthreads();

    // phases B+C, chunked: exp into LDS, accumulate unnormalized sums in regs
    float acc0 = 0.f, acc1 = 0.f;
    int h0 = tid >> 6, h1 = 4 + (tid >> 6);
    for (int c0 = 0; c0 <= deg; c0 += CHUNK) {
        int cnt = min(CHUNK, deg + 1 - c0);
        if (tid < cnt) {
            int i = c0 + tid;
            ssrc[tid] = (i == deg) ? d : csrc[beg + i];
        }
        __syncthreads();
        for (int p = tid; p < cnt * HEADS; p += 256) {
            int j = p >> 3, hh = p & 7;
            int s = ssrc[j];
            float v = a_s[s * HEADS + hh] + sad[hh];
            v = v >= 0.f ? v : 0.2f * v;
            float ex = __expf(v - smax[hh]);
            sex[j][hh] = ex;
            atomicAdd(&sden[hh], ex);
        }
        __syncthreads();
        for (int j = 0; j < cnt; ++j) {
            int s = ssrc[j];
            float e0 = sex[j][h0], e1 = sex[j][h1];
            acc0 += e0 * h[(size_t)s * F512 + tid];
            acc1 += e1 * h[(size_t)s * F512 + 256 + tid];
        }
        __syncthreads();
    }

    float o0 = acc0 / (sden[h0] + 1e-16f) + bias[tid];
    float o1 = acc1 / (sden[h1] + 1e-16f) + bias[256 + tid];
    if (ELU) {
        o0 = o0 > 0.f ? o0 : expm1f(o0);
        o1 = o1 > 0.f ? o1 : expm1f(o1);
    }
    out[(size_t)d * F512 + tid] = o0;
    out[(size_t)d * F512 + 256 + tid] = o1;
}

// Layer 3: wave per destination node, 3 channels, single head. No ELU.
__global__ __launch_bounds__(256) void gat_aggr3_fused(
    const int* __restrict__ rowptr, const int* __restrict__ csrc,
    const float* __restrict__ a_s, const float* __restrict__ a_d,
    const float* __restrict__ h3, const float* __restrict__ b3,
    float* __restrict__ out, int N) {
    int w = (blockIdx.x * blockDim.x + threadIdx.x) >> 6;
    int lane = threadIdx.x & 63;
    if (w >= N) return;
    int d = w;
    int beg = rowptr[d], deg = rowptr[d + 1] - beg;
    float ad = a_d[d];
    float m = -INFINITY;
    for (int i = lane; i <= deg; i += 64) {
        int s = (i == deg) ? d : csrc[beg + i];
        float v = a_s[s] + ad;
        v = v >= 0.f ? v : 0.2f * v;
        m = fmaxf(m, v);
    }
    for (int off = 32; off; off >>= 1) m = fmaxf(m, __shfl_xor(m, off));
    float den = 0.f, c0 = 0.f, c1 = 0.f, c2 = 0.f;
    for (int i = lane; i <= deg; i += 64) {
        int s = (i == deg) ? d : csrc[beg + i];
        float v = a_s[s] + ad;
        v = v >= 0.f ? v : 0.2f * v;
        float ex = __expf(v - m);
        den += ex;
        c0 += ex * h3[(size_t)s * 3 + 0];
        c1 += ex * h3[(size_t)s * 3 + 1];
        c2 += ex * h3[(size_t)s * 3 + 2];
    }
    for (int off = 32; off; off >>= 1) {
        den += __shfl_xor(den, off);
        c0 += __shfl_xor(c0, off);
        c1 += __shfl_xor(c1, off);
        c2 += __shfl_xor(c2, off);
    }
    if (lane == 0) {
        float inv = 1.f / (den + 1e-16f);
        out[(size_t)d * 3 + 0] = c0 * inv + b3[0];
        out[(size_t)d * 3 + 1] = c1 * inv + b3[1];
        out[(size_t)d * 3 + 2] = c2 * inv + b3[2];
    }
}

static inline int cdiv(long long a, long long b) { return (int)((a + b - 1) / b); }

extern "C" void kernel_launch(void* const* d_in, const int* in_sizes, int n_in,
                              void* d_out, int out_size, void* d_ws, size_t ws_size,
                              hipStream_t stream) {
    const int N = in_sizes[0] / 12;
    const int E = in_sizes[1] / 2;
    const float* x     = (const float*)d_in[0];
    const int*   ei    = (const int*)d_in[1];
    const float* W1    = (const float*)d_in[2];
    const float* asrc1 = (const float*)d_in[3];
    const float* adst1 = (const float*)d_in[4];
    const float* b1    = (const float*)d_in[5];
    const float* W2    = (const float*)d_in[6];
    const float* asrc2 = (const float*)d_in[7];
    const float* adst2 = (const float*)d_in[8];
    const float* b2    = (const float*)d_in[9];
    const float* W3    = (const float*)d_in[10];
    const float* asrc3 = (const float*)d_in[11];
    const float* adst3 = (const float*)d_in[12];
    const float* b3    = (const float*)d_in[13];

    const int* srcv = ei;
    const int* dstv = ei + E;
    float* out = (float*)d_out;

    char* ws = (char*)d_ws;
    size_t szH = (size_t)N * F512 * sizeof(float);
    float* hA  = (float*)ws;                         // N*512
    float* hB  = (float*)(ws + szH);                 // N*512
    char*  p   = ws + 2 * szH;
    float* a_s   = (float*)p;            p += (size_t)N * HEADS * 4;
    float* a_d   = (float*)p;            p += (size_t)N * HEADS * 4;
    float* h3    = (float*)p;            p += (size_t)N * 3 * 4;
    int*   cnt   = (int*)p;              p += (size_t)N * 4;
    int*   excl  = (int*)p;              p += (size_t)N * 4;
    int*   rowptr= (int*)p;              p += (size_t)(N + 1) * 4;
    int*   fill  = (int*)p;              p += (size_t)N * 4;
    int*   bsum  = (int*)p;              p += 4096;
    int*   csrc  = (int*)p;              p += (size_t)E * 4;

    const size_t totH = (size_t)N * F512;
    const int nb = cdiv(N, 1024);

    // ---- CSR build (shared by all 3 layers) ----
    hipMemsetAsync(cnt, 0, (size_t)N * 4, stream);
    hist_kernel<<<cdiv(E, 256), 256, 0, stream>>>(dstv, E, cnt);
    scan_block_kernel<<<nb, 1024, 0, stream>>>(cnt, excl, bsum, N);
    scan_aux_kernel<<<1, 64, 0, stream>>>(bsum, nb);
    scan_add_kernel<<<cdiv(N + 1, 256), 256, 0, stream>>>(excl, bsum, rowptr, fill, N, E);
    scatter_kernel<<<cdiv(E, 256), 256, 0, stream>>>(srcv, dstv, E, fill, csrc);

    // ----------------- Layer 1 -----------------
    gemm1_kernel<<<cdiv(totH, 256), 256, 0, stream>>>(x, W1, hA, N);
    alpha8_kernel<<<cdiv((long long)N * 64, 256), 256, 0, stream>>>(hA, asrc1, adst1, a_s, a_d, N);
    gat_aggr_fused<true><<<N, 256, 0, stream>>>(rowptr, csrc, a_s, a_d, hA, b1, hB, N);

    // ----------------- Layer 2 -----------------
    {
        dim3 grid(F512 / 64, cdiv(N, 64));
        gemm_tiled<<<grid, 256, 0, stream>>>(hB, W2, hA, N, F512, F512);
    }
    alpha8_kernel<<<cdiv((long long)N * 64, 256), 256, 0, stream>>>(hA, asrc2, adst2, a_s, a_d, N);
    gat_aggr_fused<true><<<N, 256, 0, stream>>>(rowptr, csrc, a_s, a_d, hA, b2, hB, N);

    // ----------------- Layer 3 -----------------
    gemm3_kernel<<<cdiv((long long)N * 64, 256), 256, 0, stream>>>(hB, W3, h3, N);
    alpha3_kernel<<<cdiv(N, 256), 256, 0, stream>>>(h3, asrc3, adst3, a_s, a_d, N);
    gat_aggr3_fused<<<cdiv((long long)N, 4), 256, 0, stream>>>(rowptr, csrc, a_s, a_d, h3, b3, out, N);
}

// Round 3
// 806.557 us; speedup vs baseline: 3.8468x; 1.4159x over previous
//
#include <hip/hip_runtime.h>
#include <hip/hip_bf16.h>

// ---------------------------------------------------------------------------
// GAT 3-layer forward, round 3: layer-2 GEMM via split-bf16 (hi/lo) MFMA.
// C = Ah*Bh + Ah*Bl + Al*Bh accumulated in f32 -> ~f32 accuracy at bf16 rate.
// Activations for layer-2 GEMM stored PACKED: uint32 = (bf16 hi | bf16 lo<<16),
// written directly by the layer-1 aggregation epilogue (no conversion pass).
// ---------------------------------------------------------------------------

#define HEADS 8
#define HID 64
#define F512 512

typedef __bf16 bf16x8 __attribute__((ext_vector_type(8)));
typedef unsigned short u16x8 __attribute__((ext_vector_type(8)));
typedef float f32x4 __attribute__((ext_vector_type(4)));

// RNE f32 -> bf16 (bits), then split residual: f ~= hi + lo.
__device__ __forceinline__ unsigned bf16_rne(float f) {
    unsigned u = __float_as_uint(f);
    return (u + 0x7FFFu + ((u >> 16) & 1u)) >> 16;
}
__device__ __forceinline__ unsigned pack_split(float f) {
    unsigned hi = bf16_rne(f);
    float r = f - __uint_as_float(hi << 16);
    unsigned lo = bf16_rne(r);
    return hi | (lo << 16);
}

// ---------------- GEMMs ----------------

// h[n][j] = sum_{k<12} x[n][k] * W1[k][j]
__global__ void gemm1_kernel(const float* __restrict__ x, const float* __restrict__ W1,
                             float* __restrict__ h, int N) {
    int idx = blockIdx.x * blockDim.x + threadIdx.x;
    if (idx >= N * F512) return;
    int n = idx >> 9, j = idx & 511;
    const float* xr = x + (size_t)n * 12;
    float acc = 0.f;
#pragma unroll
    for (int k = 0; k < 12; ++k) acc += xr[k] * W1[k * F512 + j];
    h[idx] = acc;
}

// W2 [K=512][N=512] f32  ->  BT [n][k] packed(hi,lo)
__global__ void convW2_kernel(const float* __restrict__ W2, unsigned* __restrict__ BT) {
    int tid = blockIdx.x * blockDim.x + threadIdx.x;
    if (tid >= F512 * F512) return;
    int n = tid & 511, k = tid >> 9;
    BT[(size_t)n * F512 + k] = pack_split(W2[(size_t)k * F512 + n]);
}

// Split-bf16 MFMA GEMM: C[M,512] = unpack(Ap) @ unpack(BT)^T (BT is n-major).
// 128x128 tile, BK=32, 256 threads = 4 waves (2x2 of 64x64), 16x16x32 MFMA.
__global__ __launch_bounds__(256) void gemm2_mfma(
    const unsigned* __restrict__ Ap,   // [Mpad][512] packed hi/lo
    const unsigned* __restrict__ BT,   // [512][512] packed hi/lo, n-major
    float* __restrict__ C, int M) {
    __shared__ unsigned short AsH[128 * 32], AsL[128 * 32];
    __shared__ unsigned short BsH[128 * 32], BsL[128 * 32];

    // bijective XCD-chunked swizzle (m-major logical order)
    int nwg = gridDim.x;
    int o = blockIdx.x;
    int q = nwg >> 3, r = nwg & 7, xcd = o & 7;
    int base = xcd < r ? xcd * (q + 1) : r * (q + 1) + (xcd - r) * q;
    int lg = base + (o >> 3);
    int mb = lg >> 2, nb = lg & 3;

    int tid = threadIdx.x;
    int lane = tid & 63, wv = tid >> 6;
    int wm = wv >> 1, wn = wv & 1;
    int srow = tid >> 2, schunk = tid & 3;   // staging: row, 8-elem chunk
    int seg = lane >> 4;                     // fragment k-segment

    f32x4 acc[4][4] = {};

    for (int k0 = 0; k0 < F512; k0 += 32) {
#pragma unroll
        for (int u = 0; u < 2; ++u) {
            int rr = srow + u * 64;
            int off = rr * 32 + ((schunk ^ ((rr >> 1) & 3)) << 3);
            {
                const uint4* g = (const uint4*)(Ap + ((size_t)(mb * 128 + rr)) * F512 + k0 + schunk * 8);
                uint4 g0 = g[0], g1 = g[1];
                uint4 hi, lo;
                hi.x = (g0.x & 0xFFFFu) | (g0.y << 16); lo.x = (g0.x >> 16) | (g0.y & 0xFFFF0000u);
                hi.y = (g0.z & 0xFFFFu) | (g0.w << 16); lo.y = (g0.z >> 16) | (g0.w & 0xFFFF0000u);
                hi.z = (g1.x & 0xFFFFu) | (g1.y << 16); lo.z = (g1.x >> 16) | (g1.y & 0xFFFF0000u);
                hi.w = (g1.z & 0xFFFFu) | (g1.w << 16); lo.w = (g1.z >> 16) | (g1.w & 0xFFFF0000u);
                *(uint4*)&AsH[off] = hi;
                *(uint4*)&AsL[off] = lo;
            }
            {
                const uint4* g = (const uint4*)(BT + ((size_t)(nb * 128 + rr)) * F512 + k0 + schunk * 8);
                uint4 g0 = g[0], g1 = g[1];
                uint4 hi, lo;
                hi.x = (g0.x & 0xFFFFu) | (g0.y << 16); lo.x = (g0.x >> 16) | (g0.y & 0xFFFF0000u);
                hi.y = (g0.z & 0xFFFFu) | (g0.w << 16); lo.y = (g0.z >> 16) | (g0.w & 0xFFFF0000u);
                hi.z = (g1.x & 0xFFFFu) | (g1.y << 16); lo.z = (g1.x >> 16) | (g1.y & 0xFFFF0000u);
                hi.w = (g1.z & 0xFFFFu) | (g1.w << 16); lo.w = (g1.z >> 16) | (g1.w & 0xFFFF0000u);
                *(uint4*)&BsH[off] = hi;
                *(uint4*)&BsL[off] = lo;
            }
        }
        __syncthreads();

        bf16x8 aH[4], aL[4], bH[4], bL[4];
#pragma unroll
        for (int mi = 0; mi < 4; ++mi) {
            int arow = wm * 64 + mi * 16 + (lane & 15);
            int aoff = arow * 32 + ((seg ^ ((arow >> 1) & 3)) << 3);
            aH[mi] = __builtin_bit_cast(bf16x8, *(const u16x8*)&AsH[aoff]);
            aL[mi] = __builtin_bit_cast(bf16x8, *(const u16x8*)&AsL[aoff]);
        }
#pragma unroll
        for (int ni = 0; ni < 4; ++ni) {
            int brow = wn * 64 + ni * 16 + (lane & 15);
            int boff = brow * 32 + ((seg ^ ((brow >> 1) & 3)) << 3);
            bH[ni] = __builtin_bit_cast(bf16x8, *(const u16x8*)&BsH[boff]);
            bL[ni] = __builtin_bit_cast(bf16x8, *(const u16x8*)&BsL[boff]);
        }
#pragma unroll
        for (int mi = 0; mi < 4; ++mi)
#pragma unroll
            for (int ni = 0; ni < 4; ++ni) {
                acc[mi][ni] = __builtin_amdgcn_mfma_f32_16x16x32_bf16(aH[mi], bH[ni], acc[mi][ni], 0, 0, 0);
                acc[mi][ni] = __builtin_amdgcn_mfma_f32_16x16x32_bf16(aH[mi], bL[ni], acc[mi][ni], 0, 0, 0);
                acc[mi][ni] = __builtin_amdgcn_mfma_f32_16x16x32_bf16(aL[mi], bH[ni], acc[mi][ni], 0, 0, 0);
            }
        __syncthreads();
    }

#pragma unroll
    for (int mi = 0; mi < 4; ++mi) {
#pragma unroll
        for (int ni = 0; ni < 4; ++ni) {
            int rbase = mb * 128 + wm * 64 + mi * 16 + (lane >> 4) * 4;
            int c = nb * 128 + wn * 64 + ni * 16 + (lane & 15);
#pragma unroll
            for (int i = 0; i < 4; ++i) {
                int row = rbase + i;
                if (row < M) C[(size_t)row * F512 + c] = acc[mi][ni][i];
            }
        }
    }
}

// Layer 3 projection: h3[n,0..2] = h[n,:] @ W3, wave per node.
__global__ void gemm3_kernel(const float* __restrict__ h, const float* __restrict__ W3,
                             float* __restrict__ h3, int N) {
    int wave = (blockIdx.x * blockDim.x + threadIdx.x) >> 6;
    int lane = threadIdx.x & 63;
    if (wave >= N) return;
    float a0 = 0.f, a1 = 0.f, a2 = 0.f;
    for (int k = lane; k < F512; k += 64) {
        float v = h[(size_t)wave * F512 + k];
        a0 += v * W3[k * 3 + 0];
        a1 += v * W3[k * 3 + 1];
        a2 += v * W3[k * 3 + 2];
    }
    for (int off = 32; off; off >>= 1) {
        a0 += __shfl_down(a0, off);
        a1 += __shfl_down(a1, off);
        a2 += __shfl_down(a2, off);
    }
    if (lane == 0) {
        h3[(size_t)wave * 3 + 0] = a0;
        h3[(size_t)wave * 3 + 1] = a1;
        h3[(size_t)wave * 3 + 2] = a2;
    }
}

// ---------------- alpha coefficients ----------------

__global__ void alpha8_kernel(const float* __restrict__ h, const float* __restrict__ asrc,
                              const float* __restrict__ adst, float* __restrict__ a_s,
                              float* __restrict__ a_d, int N) {
    int wave = (blockIdx.x * blockDim.x + threadIdx.x) >> 6;
    int lane = threadIdx.x & 63;
    if (wave >= N) return;
#pragma unroll
    for (int hh = 0; hh < HEADS; ++hh) {
        float v = h[(size_t)wave * F512 + hh * HID + lane];
        float s = v * asrc[hh * HID + lane];
        float d = v * adst[hh * HID + lane];
        for (int off = 32; off; off >>= 1) {
            s += __shfl_down(s, off);
            d += __shfl_down(d, off);
        }
        if (lane == 0) {
            a_s[wave * HEADS + hh] = s;
            a_d[wave * HEADS + hh] = d;
        }
    }
}

__global__ void alpha3_kernel(const float* __restrict__ h3, const float* __restrict__ asrc,
                              const float* __restrict__ adst, float* __restrict__ a_s,
                              float* __restrict__ a_d, int N) {
    int n = blockIdx.x * blockDim.x + threadIdx.x;
    if (n >= N) return;
    float s = 0.f, d = 0.f;
#pragma unroll
    for (int j = 0; j < 3; ++j) {
        float v = h3[(size_t)n * 3 + j];
        s += v * asrc[j];
        d += v * adst[j];
    }
    a_s[n] = s;
    a_d[n] = d;
}

// ---------------- CSR build ----------------

__global__ void hist_kernel(const int* __restrict__ dst, int E, int* __restrict__ cnt) {
    int e = blockIdx.x * blockDim.x + threadIdx.x;
    if (e < E) atomicAdd(&cnt[dst[e]], 1);
}

__global__ __launch_bounds__(1024) void scan_block_kernel(const int* __restrict__ cnt,
                                                          int* __restrict__ excl,
                                                          int* __restrict__ bsum, int n) {
    __shared__ int s[1024];
    int i = blockIdx.x * 1024 + threadIdx.x;
    int v = i < n ? cnt[i] : 0;
    s[threadIdx.x] = v;
    __syncthreads();
    for (int off = 1; off < 1024; off <<= 1) {
        int t = threadIdx.x >= off ? s[threadIdx.x - off] : 0;
        __syncthreads();
        s[threadIdx.x] += t;
        __syncthreads();
    }
    if (i < n) excl[i] = s[threadIdx.x] - v;
    if (threadIdx.x == 1023) bsum[blockIdx.x] = s[1023];
}

__global__ void scan_aux_kernel(int* __restrict__ bsum, int nb) {
    if (blockIdx.x == 0 && threadIdx.x == 0) {
        int acc = 0;
        for (int i = 0; i < nb; ++i) { int v = bsum[i]; bsum[i] = acc; acc += v; }
    }
}

__global__ void scan_add_kernel(const int* __restrict__ excl, const int* __restrict__ bsum,
                                int* __restrict__ rowptr, int* __restrict__ fill, int n, int E) {
    int i = blockIdx.x * blockDim.x + threadIdx.x;
    if (i < n) {
        int v = excl[i] + bsum[i >> 10];
        rowptr[i] = v;
        fill[i] = v;
    }
    if (i == 0) rowptr[n] = E;
}

__global__ void scatter_kernel(const int* __restrict__ src, const int* __restrict__ dst, int E,
                               int* __restrict__ fill, int* __restrict__ csrc) {
    int e = blockIdx.x * blockDim.x + threadIdx.x;
    if (e >= E) return;
    int pos = atomicAdd(&fill[dst[e]], 1);
    csrc[pos] = src[e];
}

// ---------------- fused segment-softmax + aggregation ----------------
// One 256-thread block per destination node. Implicit self-loop (i == deg).
// PACKED: write uint32 (bf16 hi | lo<<16) for the split-bf16 GEMM input.

template <bool ELU, bool PACKED>
__global__ __launch_bounds__(256) void gat_aggr_fused(
    const int* __restrict__ rowptr, const int* __restrict__ csrc,
    const float* __restrict__ a_s, const float* __restrict__ a_d,
    const float* __restrict__ h, const float* __restrict__ bias,
    void* __restrict__ outv, int N) {
    const int CHUNK = 64;
    __shared__ float smax[HEADS], sden[HEADS], sad[HEADS];
    __shared__ float sex[CHUNK][HEADS];
    __shared__ int ssrc[CHUNK];

    int d = blockIdx.x;
    int tid = threadIdx.x;
    int beg = rowptr[d];
    int deg = rowptr[d + 1] - beg;

    if (tid < HEADS) { sad[tid] = a_d[d * HEADS + tid]; sden[tid] = 0.f; }
    __syncthreads();

    if (tid < 64) {
        int hh = tid & 7;
        float m = -INFINITY;
        for (int i = tid >> 3; i <= deg; i += 8) {
            int s = (i == deg) ? d : csrc[beg + i];
            float v = a_s[s * HEADS + hh] + sad[hh];
            v = v >= 0.f ? v : 0.2f * v;
            m = fmaxf(m, v);
        }
        m = fmaxf(m, __shfl_xor(m, 8));
        m = fmaxf(m, __shfl_xor(m, 16));
        m = fmaxf(m, __shfl_xor(m, 32));
        if (tid < 8) smax[tid] = m;
    }
    __syncthreads();

    float acc0 = 0.f, acc1 = 0.f;
    int h0 = tid >> 6, h1 = 4 + (tid >> 6);
    for (int c0 = 0; c0 <= deg; c0 += CHUNK) {
        int cnt = min(CHUNK, deg + 1 - c0);
        if (tid < cnt) {
            int i = c0 + tid;
            ssrc[tid] = (i == deg) ? d : csrc[beg + i];
        }
        __syncthreads();
        for (int p = tid; p < cnt * HEADS; p += 256) {
            int j = p >> 3, hh = p & 7;
            int s = ssrc[j];
            float v = a_s[s * HEADS + hh] + sad[hh];
            v = v >= 0.f ? v : 0.2f * v;
            float ex = __expf(v - smax[hh]);
            sex[j][hh] = ex;
            atomicAdd(&sden[hh], ex);
        }
        __syncthreads();
        for (int j = 0; j < cnt; ++j) {
            int s = ssrc[j];
            float e0 = sex[j][h0], e1 = sex[j][h1];
            acc0 += e0 * h[(size_t)s * F512 + tid];
            acc1 += e1 * h[(size_t)s * F512 + 256 + tid];
        }
        __syncthreads();
    }

    float o0 = acc0 / (sden[h0] + 1e-16f) + bias[tid];
    float o1 = acc1 / (sden[h1] + 1e-16f) + bias[256 + tid];
    if (ELU) {
        o0 = o0 > 0.f ? o0 : expm1f(o0);
        o1 = o1 > 0.f ? o1 : expm1f(o1);
    }
    if (PACKED) {
        unsigned* o = (unsigned*)outv;
        o[(size_t)d * F512 + tid] = pack_split(o0);
        o[(size_t)d * F512 + 256 + tid] = pack_split(o1);
    } else {
        float* o = (float*)outv;
        o[(size_t)d * F512 + tid] = o0;
        o[(size_t)d * F512 + 256 + tid] = o1;
    }
}

// Layer 3: wave per destination node, 3 channels, single head. No ELU.
__global__ __launch_bounds__(256) void gat_aggr3_fused(
    const int* __restrict__ rowptr, const int* __restrict__ csrc,
    const float* __restrict__ a_s, const float* __restrict__ a_d,
    const float* __restrict__ h3, const float* __restrict__ b3,
    float* __restrict__ out, int N) {
    int w = (blockIdx.x * blockDim.x + threadIdx.x) >> 6;
    int lane = threadIdx.x & 63;
    if (w >= N) return;
    int d = w;
    int beg = rowptr[d], deg = rowptr[d + 1] - beg;
    float ad = a_d[d];
    float m = -INFINITY;
    for (int i = lane; i <= deg; i += 64) {
        int s = (i == deg) ? d : csrc[beg + i];
        float v = a_s[s] + ad;
        v = v >= 0.f ? v : 0.2f * v;
        m = fmaxf(m, v);
    }
    for (int off = 32; off; off >>= 1) m = fmaxf(m, __shfl_xor(m, off));
    float den = 0.f, c0 = 0.f, c1 = 0.f, c2 = 0.f;
    for (int i = lane; i <= deg; i += 64) {
        int s = (i == deg) ? d : csrc[beg + i];
        float v = a_s[s] + ad;
        v = v >= 0.f ? v : 0.2f * v;
        float ex = __expf(v - m);
        den += ex;
        c0 += ex * h3[(size_t)s * 3 + 0];
        c1 += ex * h3[(size_t)s * 3 + 1];
        c2 += ex * h3[(size_t)s * 3 + 2];
    }
    for (int off = 32; off; off >>= 1) {
        den += __shfl_xor(den, off);
        c0 += __shfl_xor(c0, off);
        c1 += __shfl_xor(c1, off);
        c2 += __shfl_xor(c2, off);
    }
    if (lane == 0) {
        float inv = 1.f / (den + 1e-16f);
        out[(size_t)d * 3 + 0] = c0 * inv + b3[0];
        out[(size_t)d * 3 + 1] = c1 * inv + b3[1];
        out[(size_t)d * 3 + 2] = c2 * inv + b3[2];
    }
}

static inline int cdiv(long long a, long long b) { return (int)((a + b - 1) / b); }
static inline size_t rup(size_t v) { return (v + 255) & ~(size_t)255; }

extern "C" void kernel_launch(void* const* d_in, const int* in_sizes, int n_in,
                              void* d_out, int out_size, void* d_ws, size_t ws_size,
                              hipStream_t stream) {
    const int N = in_sizes[0] / 12;
    const int E = in_sizes[1] / 2;
    const float* x     = (const float*)d_in[0];
    const int*   ei    = (const int*)d_in[1];
    const float* W1    = (const float*)d_in[2];
    const float* asrc1 = (const float*)d_in[3];
    const float* adst1 = (const float*)d_in[4];
    const float* b1    = (const float*)d_in[5];
    const float* W2    = (const float*)d_in[6];
    const float* asrc2 = (const float*)d_in[7];
    const float* adst2 = (const float*)d_in[8];
    const float* b2    = (const float*)d_in[9];
    const float* W3    = (const float*)d_in[10];
    const float* asrc3 = (const float*)d_in[11];
    const float* adst3 = (const float*)d_in[12];
    const float* b3    = (const float*)d_in[13];

    const int* srcv = ei;
    const int* dstv = ei + E;
    float* out = (float*)d_out;

    const int Mpad = cdiv(N, 128) * 128;
    char* ws = (char*)d_ws;
    size_t szH  = rup((size_t)N * F512 * 4);
    size_t szHp = rup((size_t)Mpad * F512 * 4);
    float*    hA   = (float*)ws;                    // N x 512 f32 (pre-aggr h)
    char*     hBc  = ws + szH;                      // Mpad x 512: packed OR f32
    unsigned* hBp  = (unsigned*)hBc;
    float*    hBf  = (float*)hBc;
    char* p = hBc + szHp;
    float* a_s    = (float*)p;  p += rup((size_t)N * HEADS * 4);
    float* a_d    = (float*)p;  p += rup((size_t)N * HEADS * 4);
    float* h3     = (float*)p;  p += rup((size_t)N * 3 * 4);
    int*   cnt    = (int*)p;    p += rup((size_t)N * 4);
    int*   excl   = (int*)p;    p += rup((size_t)N * 4);
    int*   rowptr = (int*)p;    p += rup((size_t)(N + 1) * 4);
    int*   fill   = (int*)p;    p += rup((size_t)N * 4);
    int*   bsum   = (int*)p;    p += rup(4096);
    int*   csrc   = (int*)p;    p += rup((size_t)E * 4);
    unsigned* BT  = (unsigned*)p;  // 512*512 packed = 1 MB

    const size_t totH = (size_t)N * F512;
    const int nb = cdiv(N, 1024);

    // ---- CSR build (shared by all 3 layers) + W2 split-convert ----
    hipMemsetAsync(cnt, 0, (size_t)N * 4, stream);
    hist_kernel<<<cdiv(E, 256), 256, 0, stream>>>(dstv, E, cnt);
    scan_block_kernel<<<nb, 1024, 0, stream>>>(cnt, excl, bsum, N);
    scan_aux_kernel<<<1, 64, 0, stream>>>(bsum, nb);
    scan_add_kernel<<<cdiv(N + 1, 256), 256, 0, stream>>>(excl, bsum, rowptr, fill, N, E);
    scatter_kernel<<<cdiv(E, 256), 256, 0, stream>>>(srcv, dstv, E, fill, csrc);
    convW2_kernel<<<cdiv((long long)F512 * F512, 256), 256, 0, stream>>>(W2, BT);

    // ----------------- Layer 1 -----------------
    gemm1_kernel<<<cdiv(totH, 256), 256, 0, stream>>>(x, W1, hA, N);
    alpha8_kernel<<<cdiv((long long)N * 64, 256), 256, 0, stream>>>(hA, asrc1, adst1, a_s, a_d, N);
    gat_aggr_fused<true, true><<<N, 256, 0, stream>>>(rowptr, csrc, a_s, a_d, hA, b1, hBp, N);

    // ----------------- Layer 2 -----------------
    gemm2_mfma<<<(Mpad / 128) * 4, 256, 0, stream>>>(hBp, BT, hA, N);
    alpha8_kernel<<<cdiv((long long)N * 64, 256), 256, 0, stream>>>(hA, asrc2, adst2, a_s, a_d, N);
    gat_aggr_fused<true, false><<<N, 256, 0, stream>>>(rowptr, csrc, a_s, a_d, hA, b2, hBf, N);

    // ----------------- Layer 3 -----------------
    gemm3_kernel<<<cdiv((long long)N * 64, 256), 256, 0, stream>>>(hBf, W3, h3, N);
    alpha3_kernel<<<cdiv(N, 256), 256, 0, stream>>>(h3, asrc3, adst3, a_s, a_d, N);
    gat_aggr3_fused<<<cdiv((long long)N, 4), 256, 0, stream>>>(rowptr, csrc, a_s, a_d, h3, b3, out, N);
}

// Round 4
// 734.603 us; speedup vs baseline: 4.2236x; 1.0979x over previous
//
#include <hip/hip_runtime.h>
#include <hip/hip_bf16.h>
#include <hip/hip_fp16.h>

// ---------------------------------------------------------------------------
// GAT 3-layer forward, round 4: fp16 feature storage for the edge gathers
// (halves the random-gather footprint: 102 MB -> 51 MB, L3-resident).
// Layer-2 GEMM: split-bf16 MFMA (Ah*Bh + Ah*Bl + Al*Bh) ~ f32 accuracy.
// ---------------------------------------------------------------------------

#define HEADS 8
#define HID 64
#define F512 512

typedef __bf16 bf16x8 __attribute__((ext_vector_type(8)));
typedef unsigned short u16x8 __attribute__((ext_vector_type(8)));
typedef float f32x4 __attribute__((ext_vector_type(4)));

// RNE f32 -> bf16 (bits), then split residual: f ~= hi + lo.
__device__ __forceinline__ unsigned bf16_rne(float f) {
    unsigned u = __float_as_uint(f);
    return (u + 0x7FFFu + ((u >> 16) & 1u)) >> 16;
}
__device__ __forceinline__ unsigned pack_split(float f) {
    unsigned hi = bf16_rne(f);
    float r = f - __uint_as_float(hi << 16);
    unsigned lo = bf16_rne(r);
    return hi | (lo << 16);
}

// ---------------- GEMMs ----------------

// h16[n][j] = fp16( sum_{k<12} x[n][k] * W1[k][j] )
__global__ void gemm1_kernel(const float* __restrict__ x, const float* __restrict__ W1,
                             __half* __restrict__ h, int N) {
    int idx = blockIdx.x * blockDim.x + threadIdx.x;
    if (idx >= N * F512) return;
    int n = idx >> 9, j = idx & 511;
    const float* xr = x + (size_t)n * 12;
    float acc = 0.f;
#pragma unroll
    for (int k = 0; k < 12; ++k) acc += xr[k] * W1[k * F512 + j];
    h[idx] = __float2half_rn(acc);
}

// W2 [K=512][N=512] f32  ->  BT [n][k] packed(hi,lo)
__global__ void convW2_kernel(const float* __restrict__ W2, unsigned* __restrict__ BT) {
    int tid = blockIdx.x * blockDim.x + threadIdx.x;
    if (tid >= F512 * F512) return;
    int n = tid & 511, k = tid >> 9;
    BT[(size_t)n * F512 + k] = pack_split(W2[(size_t)k * F512 + n]);
}

// Split-bf16 MFMA GEMM: C[M,512] = unpack(Ap) @ unpack(BT)^T, fp16 output.
// 128x128 tile, BK=32, 256 threads = 4 waves (2x2 of 64x64), 16x16x32 MFMA.
__global__ __launch_bounds__(256) void gemm2_mfma(
    const unsigned* __restrict__ Ap,   // [Mpad][512] packed hi/lo
    const unsigned* __restrict__ BT,   // [512][512] packed hi/lo, n-major
    __half* __restrict__ C, int M) {
    __shared__ unsigned short AsH[128 * 32], AsL[128 * 32];
    __shared__ unsigned short BsH[128 * 32], BsL[128 * 32];

    // bijective XCD-chunked swizzle (m-major logical order)
    int nwg = gridDim.x;
    int o = blockIdx.x;
    int q = nwg >> 3, r = nwg & 7, xcd = o & 7;
    int base = xcd < r ? xcd * (q + 1) : r * (q + 1) + (xcd - r) * q;
    int lg = base + (o >> 3);
    int mb = lg >> 2, nb = lg & 3;

    int tid = threadIdx.x;
    int lane = tid & 63, wv = tid >> 6;
    int wm = wv >> 1, wn = wv & 1;
    int srow = tid >> 2, schunk = tid & 3;
    int seg = lane >> 4;

    f32x4 acc[4][4] = {};

    for (int k0 = 0; k0 < F512; k0 += 32) {
#pragma unroll
        for (int u = 0; u < 2; ++u) {
            int rr = srow + u * 64;
            int off = rr * 32 + ((schunk ^ ((rr >> 1) & 3)) << 3);
            {
                const uint4* g = (const uint4*)(Ap + ((size_t)(mb * 128 + rr)) * F512 + k0 + schunk * 8);
                uint4 g0 = g[0], g1 = g[1];
                uint4 hi, lo;
                hi.x = (g0.x & 0xFFFFu) | (g0.y << 16); lo.x = (g0.x >> 16) | (g0.y & 0xFFFF0000u);
                hi.y = (g0.z & 0xFFFFu) | (g0.w << 16); lo.y = (g0.z >> 16) | (g0.w & 0xFFFF0000u);
                hi.z = (g1.x & 0xFFFFu) | (g1.y << 16); lo.z = (g1.x >> 16) | (g1.y & 0xFFFF0000u);
                hi.w = (g1.z & 0xFFFFu) | (g1.w << 16); lo.w = (g1.z >> 16) | (g1.w & 0xFFFF0000u);
                *(uint4*)&AsH[off] = hi;
                *(uint4*)&AsL[off] = lo;
            }
            {
                const uint4* g = (const uint4*)(BT + ((size_t)(nb * 128 + rr)) * F512 + k0 + schunk * 8);
                uint4 g0 = g[0], g1 = g[1];
                uint4 hi, lo;
                hi.x = (g0.x & 0xFFFFu) | (g0.y << 16); lo.x = (g0.x >> 16) | (g0.y & 0xFFFF0000u);
                hi.y = (g0.z & 0xFFFFu) | (g0.w << 16); lo.y = (g0.z >> 16) | (g0.w & 0xFFFF0000u);
                hi.z = (g1.x & 0xFFFFu) | (g1.y << 16); lo.z = (g1.x >> 16) | (g1.y & 0xFFFF0000u);
                hi.w = (g1.z & 0xFFFFu) | (g1.w << 16); lo.w = (g1.z >> 16) | (g1.w & 0xFFFF0000u);
                *(uint4*)&BsH[off] = hi;
                *(uint4*)&BsL[off] = lo;
            }
        }
        __syncthreads();

        bf16x8 aH[4], aL[4], bH[4], bL[4];
#pragma unroll
        for (int mi = 0; mi < 4; ++mi) {
            int arow = wm * 64 + mi * 16 + (lane & 15);
            int aoff = arow * 32 + ((seg ^ ((arow >> 1) & 3)) << 3);
            aH[mi] = __builtin_bit_cast(bf16x8, *(const u16x8*)&AsH[aoff]);
            aL[mi] = __builtin_bit_cast(bf16x8, *(const u16x8*)&AsL[aoff]);
        }
#pragma unroll
        for (int ni = 0; ni < 4; ++ni) {
            int brow = wn * 64 + ni * 16 + (lane & 15);
            int boff = brow * 32 + ((seg ^ ((brow >> 1) & 3)) << 3);
            bH[ni] = __builtin_bit_cast(bf16x8, *(const u16x8*)&BsH[boff]);
            bL[ni] = __builtin_bit_cast(bf16x8, *(const u16x8*)&BsL[boff]);
        }
#pragma unroll
        for (int mi = 0; mi < 4; ++mi)
#pragma unroll
            for (int ni = 0; ni < 4; ++ni) {
                acc[mi][ni] = __builtin_amdgcn_mfma_f32_16x16x32_bf16(aH[mi], bH[ni], acc[mi][ni], 0, 0, 0);
                acc[mi][ni] = __builtin_amdgcn_mfma_f32_16x16x32_bf16(aH[mi], bL[ni], acc[mi][ni], 0, 0, 0);
                acc[mi][ni] = __builtin_amdgcn_mfma_f32_16x16x32_bf16(aL[mi], bH[ni], acc[mi][ni], 0, 0, 0);
            }
        __syncthreads();
    }

#pragma unroll
    for (int mi = 0; mi < 4; ++mi) {
#pragma unroll
        for (int ni = 0; ni < 4; ++ni) {
            int rbase = mb * 128 + wm * 64 + mi * 16 + (lane >> 4) * 4;
            int c = nb * 128 + wn * 64 + ni * 16 + (lane & 15);
#pragma unroll
            for (int i = 0; i < 4; ++i) {
                int row = rbase + i;
                if (row < M) C[(size_t)row * F512 + c] = __float2half_rn(acc[mi][ni][i]);
            }
        }
    }
}

// Layer 3 projection: h3[n,0..2] = h[n,:] @ W3, wave per node (f32 input).
__global__ void gemm3_kernel(const float* __restrict__ h, const float* __restrict__ W3,
                             float* __restrict__ h3, int N) {
    int wave = (blockIdx.x * blockDim.x + threadIdx.x) >> 6;
    int lane = threadIdx.x & 63;
    if (wave >= N) return;
    float a0 = 0.f, a1 = 0.f, a2 = 0.f;
    for (int k = lane; k < F512; k += 64) {
        float v = h[(size_t)wave * F512 + k];
        a0 += v * W3[k * 3 + 0];
        a1 += v * W3[k * 3 + 1];
        a2 += v * W3[k * 3 + 2];
    }
    for (int off = 32; off; off >>= 1) {
        a0 += __shfl_down(a0, off);
        a1 += __shfl_down(a1, off);
        a2 += __shfl_down(a2, off);
    }
    if (lane == 0) {
        h3[(size_t)wave * 3 + 0] = a0;
        h3[(size_t)wave * 3 + 1] = a1;
        h3[(size_t)wave * 3 + 2] = a2;
    }
}

// ---------------- alpha coefficients ----------------

__global__ void alpha8_kernel(const __half* __restrict__ h, const float* __restrict__ asrc,
                              const float* __restrict__ adst, float* __restrict__ a_s,
                              float* __restrict__ a_d, int N) {
    int wave = (blockIdx.x * blockDim.x + threadIdx.x) >> 6;
    int lane = threadIdx.x & 63;
    if (wave >= N) return;
#pragma unroll
    for (int hh = 0; hh < HEADS; ++hh) {
        float v = __half2float(h[(size_t)wave * F512 + hh * HID + lane]);
        float s = v * asrc[hh * HID + lane];
        float d = v * adst[hh * HID + lane];
        for (int off = 32; off; off >>= 1) {
            s += __shfl_down(s, off);
            d += __shfl_down(d, off);
        }
        if (lane == 0) {
            a_s[wave * HEADS + hh] = s;
            a_d[wave * HEADS + hh] = d;
        }
    }
}

__global__ void alpha3_kernel(const float* __restrict__ h3, const float* __restrict__ asrc,
                              const float* __restrict__ adst, float* __restrict__ a_s,
                              float* __restrict__ a_d, int N) {
    int n = blockIdx.x * blockDim.x + threadIdx.x;
    if (n >= N) return;
    float s = 0.f, d = 0.f;
#pragma unroll
    for (int j = 0; j < 3; ++j) {
        float v = h3[(size_t)n * 3 + j];
        s += v * asrc[j];
        d += v * adst[j];
    }
    a_s[n] = s;
    a_d[n] = d;
}

// ---------------- CSR build ----------------

__global__ void hist_kernel(const int* __restrict__ dst, int E, int* __restrict__ cnt) {
    int e = blockIdx.x * blockDim.x + threadIdx.x;
    if (e < E) atomicAdd(&cnt[dst[e]], 1);
}

__global__ __launch_bounds__(1024) void scan_block_kernel(const int* __restrict__ cnt,
                                                          int* __restrict__ excl,
                                                          int* __restrict__ bsum, int n) {
    __shared__ int s[1024];
    int i = blockIdx.x * 1024 + threadIdx.x;
    int v = i < n ? cnt[i] : 0;
    s[threadIdx.x] = v;
    __syncthreads();
    for (int off = 1; off < 1024; off <<= 1) {
        int t = threadIdx.x >= off ? s[threadIdx.x - off] : 0;
        __syncthreads();
        s[threadIdx.x] += t;
        __syncthreads();
    }
    if (i < n) excl[i] = s[threadIdx.x] - v;
    if (threadIdx.x == 1023) bsum[blockIdx.x] = s[1023];
}

__global__ void scan_aux_kernel(int* __restrict__ bsum, int nb) {
    if (blockIdx.x == 0 && threadIdx.x == 0) {
        int acc = 0;
        for (int i = 0; i < nb; ++i) { int v = bsum[i]; bsum[i] = acc; acc += v; }
    }
}

__global__ void scan_add_kernel(const int* __restrict__ excl, const int* __restrict__ bsum,
                                int* __restrict__ rowptr, int* __restrict__ fill, int n, int E) {
    int i = blockIdx.x * blockDim.x + threadIdx.x;
    if (i < n) {
        int v = excl[i] + bsum[i >> 10];
        rowptr[i] = v;
        fill[i] = v;
    }
    if (i == 0) rowptr[n] = E;
}

__global__ void scatter_kernel(const int* __restrict__ src, const int* __restrict__ dst, int E,
                               int* __restrict__ fill, int* __restrict__ csrc) {
    int e = blockIdx.x * blockDim.x + threadIdx.x;
    if (e >= E) return;
    int pos = atomicAdd(&fill[dst[e]], 1);
    csrc[pos] = src[e];
}

// ---------------- fused segment-softmax + aggregation ----------------
// One 256-thread block per destination node; thread t owns channels 2t,2t+1
// (head = t>>5). Gather source is fp16 (__half2 loads). Implicit self-loop.
// PACKED: write uint32 (bf16 hi | lo<<16) pairs for the split-bf16 GEMM.

template <bool ELU, bool PACKED>
__global__ __launch_bounds__(256) void gat_aggr_fused(
    const int* __restrict__ rowptr, const int* __restrict__ csrc,
    const float* __restrict__ a_s, const float* __restrict__ a_d,
    const __half2* __restrict__ h2, const float* __restrict__ bias,
    void* __restrict__ outv, int N) {
    const int CHUNK = 64;
    __shared__ float smax[HEADS], sden[HEADS], sad[HEADS];
    __shared__ float sex[CHUNK][HEADS];
    __shared__ int ssrc[CHUNK];

    int d = blockIdx.x;
    int tid = threadIdx.x;
    int beg = rowptr[d];
    int deg = rowptr[d + 1] - beg;
    int hh = tid >> 5;   // head for this thread's channel pair

    if (tid < HEADS) { sad[tid] = a_d[d * HEADS + tid]; sden[tid] = 0.f; }
    __syncthreads();

    // phase A: per-head max (threads 0..63: head = tid&7, edge stride 8)
    if (tid < 64) {
        int hq = tid & 7;
        float m = -INFINITY;
        for (int i = tid >> 3; i <= deg; i += 8) {
            int s = (i == deg) ? d : csrc[beg + i];
            float v = a_s[s * HEADS + hq] + sad[hq];
            v = v >= 0.f ? v : 0.2f * v;
            m = fmaxf(m, v);
        }
        m = fmaxf(m, __shfl_xor(m, 8));
        m = fmaxf(m, __shfl_xor(m, 16));
        m = fmaxf(m, __shfl_xor(m, 32));
        if (tid < 8) smax[tid] = m;
    }
    __syncthreads();

    // phases B+C, chunked: exp into LDS, accumulate channel-pair sums in regs
    float accx = 0.f, accy = 0.f;
    for (int c0 = 0; c0 <= deg; c0 += CHUNK) {
        int cnt = min(CHUNK, deg + 1 - c0);
        if (tid < cnt) {
            int i = c0 + tid;
            ssrc[tid] = (i == deg) ? d : csrc[beg + i];
        }
        __syncthreads();
        for (int p = tid; p < cnt * HEADS; p += 256) {
            int j = p >> 3, hq = p & 7;
            int s = ssrc[j];
            float v = a_s[s * HEADS + hq] + sad[hq];
            v = v >= 0.f ? v : 0.2f * v;
            float ex = __expf(v - smax[hq]);
            sex[j][hq] = ex;
            atomicAdd(&sden[hq], ex);
        }
        __syncthreads();
        for (int j = 0; j < cnt; ++j) {
            int s = ssrc[j];
            float ex = sex[j][hh];
            float2 f = __half22float2(h2[(size_t)s * 256 + tid]);
            accx += ex * f.x;
            accy += ex * f.y;
        }
        __syncthreads();
    }

    float inv = 1.f / (sden[hh] + 1e-16f);
    float2 bb = ((const float2*)bias)[tid];
    float o0 = accx * inv + bb.x;
    float o1 = accy * inv + bb.y;
    if (ELU) {
        o0 = o0 > 0.f ? o0 : expm1f(o0);
        o1 = o1 > 0.f ? o1 : expm1f(o1);
    }
    if (PACKED) {
        uint2 pk = make_uint2(pack_split(o0), pack_split(o1));
        ((uint2*)outv)[(size_t)d * 256 + tid] = pk;
    } else {
        ((float2*)outv)[(size_t)d * 256 + tid] = make_float2(o0, o1);
    }
}

// Layer 3: wave per destination node, 3 channels, single head. No ELU.
__global__ __launch_bounds__(256) void gat_aggr3_fused(
    const int* __restrict__ rowptr, const int* __restrict__ csrc,
    const float* __restrict__ a_s, const float* __restrict__ a_d,
    const float* __restrict__ h3, const float* __restrict__ b3,
    float* __restrict__ out, int N) {
    int w = (blockIdx.x * blockDim.x + threadIdx.x) >> 6;
    int lane = threadIdx.x & 63;
    if (w >= N) return;
    int d = w;
    int beg = rowptr[d], deg = rowptr[d + 1] - beg;
    float ad = a_d[d];
    float m = -INFINITY;
    for (int i = lane; i <= deg; i += 64) {
        int s = (i == deg) ? d : csrc[beg + i];
        float v = a_s[s] + ad;
        v = v >= 0.f ? v : 0.2f * v;
        m = fmaxf(m, v);
    }
    for (int off = 32; off; off >>= 1) m = fmaxf(m, __shfl_xor(m, off));
    float den = 0.f, c0 = 0.f, c1 = 0.f, c2 = 0.f;
    for (int i = lane; i <= deg; i += 64) {
        int s = (i == deg) ? d : csrc[beg + i];
        float v = a_s[s] + ad;
        v = v >= 0.f ? v : 0.2f * v;
        float ex = __expf(v - m);
        den += ex;
        c0 += ex * h3[(size_t)s * 3 + 0];
        c1 += ex * h3[(size_t)s * 3 + 1];
        c2 += ex * h3[(size_t)s * 3 + 2];
    }
    for (int off = 32; off; off >>= 1) {
        den += __shfl_xor(den, off);
        c0 += __shfl_xor(c0, off);
        c1 += __shfl_xor(c1, off);
        c2 += __shfl_xor(c2, off);
    }
    if (lane == 0) {
        float inv = 1.f / (den + 1e-16f);
        out[(size_t)d * 3 + 0] = c0 * inv + b3[0];
        out[(size_t)d * 3 + 1] = c1 * inv + b3[1];
        out[(size_t)d * 3 + 2] = c2 * inv + b3[2];
    }
}

static inline int cdiv(long long a, long long b) { return (int)((a + b - 1) / b); }
static inline size_t rup(size_t v) { return (v + 255) & ~(size_t)255; }

extern "C" void kernel_launch(void* const* d_in, const int* in_sizes, int n_in,
                              void* d_out, int out_size, void* d_ws, size_t ws_size,
                              hipStream_t stream) {
    const int N = in_sizes[0] / 12;
    const int E = in_sizes[1] / 2;
    const float* x     = (const float*)d_in[0];
    const int*   ei    = (const int*)d_in[1];
    const float* W1    = (const float*)d_in[2];
    const float* asrc1 = (const float*)d_in[3];
    const float* adst1 = (const float*)d_in[4];
    const float* b1    = (const float*)d_in[5];
    const float* W2    = (const float*)d_in[6];
    const float* asrc2 = (const float*)d_in[7];
    const float* adst2 = (const float*)d_in[8];
    const float* b2    = (const float*)d_in[9];
    const float* W3    = (const float*)d_in[10];
    const float* asrc3 = (const float*)d_in[11];
    const float* adst3 = (const float*)d_in[12];
    const float* b3    = (const float*)d_in[13];

    const int* srcv = ei;
    const int* dstv = ei + E;
    float* out = (float*)d_out;

    const int Mpad = cdiv(N, 128) * 128;
    char* ws = (char*)d_ws;
    size_t szH16 = rup((size_t)N * F512 * 2);        // fp16 features
    size_t szHp  = rup((size_t)Mpad * F512 * 4);     // packed split-bf16
    size_t szHf  = rup((size_t)N * F512 * 4);        // f32 (layer-2 output)
    __half*   h16 = (__half*)ws;
    unsigned* hBp = (unsigned*)(ws + szH16);
    float*    hBf = (float*)(ws + szH16 + szHp);
    char* p = ws + szH16 + szHp + szHf;
    float* a_s    = (float*)p;  p += rup((size_t)N * HEADS * 4);
    float* a_d    = (float*)p;  p += rup((size_t)N * HEADS * 4);
    float* h3     = (float*)p;  p += rup((size_t)N * 3 * 4);
    int*   cnt    = (int*)p;    p += rup((size_t)N * 4);
    int*   excl   = (int*)p;    p += rup((size_t)N * 4);
    int*   rowptr = (int*)p;    p += rup((size_t)(N + 1) * 4);
    int*   fill   = (int*)p;    p += rup((size_t)N * 4);
    int*   bsum   = (int*)p;    p += rup(4096);
    int*   csrc   = (int*)p;    p += rup((size_t)E * 4);
    unsigned* BT  = (unsigned*)p;  // 512*512 packed = 1 MB

    const size_t totH = (size_t)N * F512;
    const int nb = cdiv(N, 1024);

    // ---- CSR build (shared by all 3 layers) + W2 split-convert ----
    hipMemsetAsync(cnt, 0, (size_t)N * 4, stream);
    hist_kernel<<<cdiv(E, 256), 256, 0, stream>>>(dstv, E, cnt);
    scan_block_kernel<<<nb, 1024, 0, stream>>>(cnt, excl, bsum, N);
    scan_aux_kernel<<<1, 64, 0, stream>>>(bsum, nb);
    scan_add_kernel<<<cdiv(N + 1, 256), 256, 0, stream>>>(excl, bsum, rowptr, fill, N, E);
    scatter_kernel<<<cdiv(E, 256), 256, 0, stream>>>(srcv, dstv, E, fill, csrc);
    convW2_kernel<<<cdiv((long long)F512 * F512, 256), 256, 0, stream>>>(W2, BT);

    // ----------------- Layer 1 -----------------
    gemm1_kernel<<<cdiv(totH, 256), 256, 0, stream>>>(x, W1, h16, N);
    alpha8_kernel<<<cdiv((long long)N * 64, 256), 256, 0, stream>>>(h16, asrc1, adst1, a_s, a_d, N);
    gat_aggr_fused<true, true><<<N, 256, 0, stream>>>(rowptr, csrc, a_s, a_d, (const __half2*)h16, b1, hBp, N);

    // ----------------- Layer 2 -----------------
    gemm2_mfma<<<(Mpad / 128) * 4, 256, 0, stream>>>(hBp, BT, h16, N);
    alpha8_kernel<<<cdiv((long long)N * 64, 256), 256, 0, stream>>>(h16, asrc2, adst2, a_s, a_d, N);
    gat_aggr_fused<true, false><<<N, 256, 0, stream>>>(rowptr, csrc, a_s, a_d, (const __half2*)h16, b2, hBf, N);

    // ----------------- Layer 3 -----------------
    gemm3_kernel<<<cdiv((long long)N * 64, 256), 256, 0, stream>>>(hBf, W3, h3, N);
    alpha3_kernel<<<cdiv(N, 256), 256, 0, stream>>>(h3, asrc3, adst3, a_s, a_d, N);
    gat_aggr3_fused<<<cdiv((long long)N, 4), 256, 0, stream>>>(rowptr, csrc, a_s, a_d, h3, b3, out, N);
}

// Round 5
// 511.625 us; speedup vs baseline: 6.0643x; 1.4358x over previous
//
#include <hip/hip_runtime.h>
#include <hip/hip_bf16.h>
#include <hip/hip_fp16.h>

// ---------------------------------------------------------------------------
// GAT 3-layer forward, round 5.
//  - wave-per-dst aggregation (16B/lane gathers, no LDS atomics, no barriers)
//  - alpha projections fused into gemm1 / gemm2 epilogues
//  - layer-2 output never materialized: h3 = h2@W3 computed in aggr epilogue
//  - layer-2 GEMM: split-bf16 MFMA (Ah*Bh + Ah*Bl + Al*Bh), f32-quality
// ---------------------------------------------------------------------------

#define HEADS 8
#define HID 64
#define F512 512

typedef __bf16 bf16x8 __attribute__((ext_vector_type(8)));
typedef unsigned short u16x8 __attribute__((ext_vector_type(8)));
typedef float f32x4 __attribute__((ext_vector_type(4)));

__device__ __forceinline__ unsigned bf16_rne(float f) {
    unsigned u = __float_as_uint(f);
    return (u + 0x7FFFu + ((u >> 16) & 1u)) >> 16;
}
__device__ __forceinline__ unsigned pack_split(float f) {
    unsigned hi = bf16_rne(f);
    float r = f - __uint_as_float(hi << 16);
    unsigned lo = bf16_rne(r);
    return hi | (lo << 16);
}

// ---------------- Layer-1 GEMM + alpha, wave per node ----------------
__global__ __launch_bounds__(256) void gemm1_fused(
    const float* __restrict__ x, const float* __restrict__ W1,
    const float* __restrict__ asrc, const float* __restrict__ adst,
    __half* __restrict__ h16, float* __restrict__ a_s, float* __restrict__ a_d,
    int N) {
    int w = (blockIdx.x * blockDim.x + threadIdx.x) >> 6;
    int l = threadIdx.x & 63;
    if (w >= N) return;
    const float* xr = x + (size_t)w * 12;
    float4 xa = *(const float4*)(xr);
    float4 xb = *(const float4*)(xr + 4);
    float4 xc = *(const float4*)(xr + 8);
    float xv[12] = {xa.x, xa.y, xa.z, xa.w, xb.x, xb.y, xb.z, xb.w, xc.x, xc.y, xc.z, xc.w};
    int c0 = l * 8;
    float o[8] = {};
#pragma unroll
    for (int k = 0; k < 12; ++k) {
        const float4* wr = (const float4*)(W1 + k * F512 + c0);
        float4 w0 = wr[0], w1 = wr[1];
        o[0] += xv[k] * w0.x; o[1] += xv[k] * w0.y; o[2] += xv[k] * w0.z; o[3] += xv[k] * w0.w;
        o[4] += xv[k] * w1.x; o[5] += xv[k] * w1.y; o[6] += xv[k] * w1.z; o[7] += xv[k] * w1.w;
    }
    __half hv[8];
#pragma unroll
    for (int k = 0; k < 8; ++k) hv[k] = __float2half_rn(o[k]);
    *(uint4*)(h16 + (size_t)w * F512 + c0) = *(uint4*)hv;
    float s = 0.f, d = 0.f;
#pragma unroll
    for (int k = 0; k < 8; ++k) { s += o[k] * asrc[c0 + k]; d += o[k] * adst[c0 + k]; }
    s += __shfl_xor(s, 1); d += __shfl_xor(d, 1);
    s += __shfl_xor(s, 2); d += __shfl_xor(d, 2);
    s += __shfl_xor(s, 4); d += __shfl_xor(d, 4);
    if ((l & 7) == 0) { a_s[w * 8 + (l >> 3)] = s; a_d[w * 8 + (l >> 3)] = d; }
}

// W2 [K=512][N=512] f32  ->  BT [n][k] packed(hi,lo)
__global__ void convW2_kernel(const float* __restrict__ W2, unsigned* __restrict__ BT) {
    int tid = blockIdx.x * blockDim.x + threadIdx.x;
    if (tid >= F512 * F512) return;
    int n = tid & 511, k = tid >> 9;
    BT[(size_t)n * F512 + k] = pack_split(W2[(size_t)k * F512 + n]);
}

// ---------------- Layer-2 split-bf16 MFMA GEMM + fused alpha ----------------
// 128x128 tile, BK=32, 4 waves (2x2 of 64x64), 16x16x32 MFMA, fp16 out.
// Each wave's 64 columns = exactly one head -> alpha computed without atomics.
__global__ __launch_bounds__(256) void gemm2_mfma(
    const unsigned* __restrict__ Ap, const unsigned* __restrict__ BT,
    const float* __restrict__ asrc2, const float* __restrict__ adst2,
    __half* __restrict__ C, float* __restrict__ a_s, float* __restrict__ a_d,
    int M) {
    __shared__ unsigned short AsH[128 * 32], AsL[128 * 32];
    __shared__ unsigned short BsH[128 * 32], BsL[128 * 32];

    int nwg = gridDim.x;
    int o = blockIdx.x;
    int q = nwg >> 3, r = nwg & 7, xcd = o & 7;
    int base = xcd < r ? xcd * (q + 1) : r * (q + 1) + (xcd - r) * q;
    int lg = base + (o >> 3);
    int mb = lg >> 2, nb = lg & 3;

    int tid = threadIdx.x;
    int lane = tid & 63, wv = tid >> 6;
    int wm = wv >> 1, wn = wv & 1;
    int srow = tid >> 2, schunk = tid & 3;
    int seg = lane >> 4;

    f32x4 acc[4][4] = {};

    for (int k0 = 0; k0 < F512; k0 += 32) {
#pragma unroll
        for (int u = 0; u < 2; ++u) {
            int rr = srow + u * 64;
            int off = rr * 32 + ((schunk ^ ((rr >> 1) & 3)) << 3);
            {
                const uint4* g = (const uint4*)(Ap + ((size_t)(mb * 128 + rr)) * F512 + k0 + schunk * 8);
                uint4 g0 = g[0], g1 = g[1];
                uint4 hi, lo;
                hi.x = (g0.x & 0xFFFFu) | (g0.y << 16); lo.x = (g0.x >> 16) | (g0.y & 0xFFFF0000u);
                hi.y = (g0.z & 0xFFFFu) | (g0.w << 16); lo.y = (g0.z >> 16) | (g0.w & 0xFFFF0000u);
                hi.z = (g1.x & 0xFFFFu) | (g1.y << 16); lo.z = (g1.x >> 16) | (g1.y & 0xFFFF0000u);
                hi.w = (g1.z & 0xFFFFu) | (g1.w << 16); lo.w = (g1.z >> 16) | (g1.w & 0xFFFF0000u);
                *(uint4*)&AsH[off] = hi;
                *(uint4*)&AsL[off] = lo;
            }
            {
                const uint4* g = (const uint4*)(BT + ((size_t)(nb * 128 + rr)) * F512 + k0 + schunk * 8);
                uint4 g0 = g[0], g1 = g[1];
                uint4 hi, lo;
                hi.x = (g0.x & 0xFFFFu) | (g0.y << 16); lo.x = (g0.x >> 16) | (g0.y & 0xFFFF0000u);
                hi.y = (g0.z & 0xFFFFu) | (g0.w << 16); lo.y = (g0.z >> 16) | (g0.w & 0xFFFF0000u);
                hi.z = (g1.x & 0xFFFFu) | (g1.y << 16); lo.z = (g1.x >> 16) | (g1.y & 0xFFFF0000u);
                hi.w = (g1.z & 0xFFFFu) | (g1.w << 16); lo.w = (g1.z >> 16) | (g1.w & 0xFFFF0000u);
                *(uint4*)&BsH[off] = hi;
                *(uint4*)&BsL[off] = lo;
            }
        }
        __syncthreads();

        bf16x8 aH[4], aL[4], bH[4], bL[4];
#pragma unroll
        for (int mi = 0; mi < 4; ++mi) {
            int arow = wm * 64 + mi * 16 + (lane & 15);
            int aoff = arow * 32 + ((seg ^ ((arow >> 1) & 3)) << 3);
            aH[mi] = __builtin_bit_cast(bf16x8, *(const u16x8*)&AsH[aoff]);
            aL[mi] = __builtin_bit_cast(bf16x8, *(const u16x8*)&AsL[aoff]);
        }
#pragma unroll
        for (int ni = 0; ni < 4; ++ni) {
            int brow = wn * 64 + ni * 16 + (lane & 15);
            int boff = brow * 32 + ((seg ^ ((brow >> 1) & 3)) << 3);
            bH[ni] = __builtin_bit_cast(bf16x8, *(const u16x8*)&BsH[boff]);
            bL[ni] = __builtin_bit_cast(bf16x8, *(const u16x8*)&BsL[boff]);
        }
#pragma unroll
        for (int mi = 0; mi < 4; ++mi)
#pragma unroll
            for (int ni = 0; ni < 4; ++ni) {
                acc[mi][ni] = __builtin_amdgcn_mfma_f32_16x16x32_bf16(aH[mi], bH[ni], acc[mi][ni], 0, 0, 0);
                acc[mi][ni] = __builtin_amdgcn_mfma_f32_16x16x32_bf16(aH[mi], bL[ni], acc[mi][ni], 0, 0, 0);
                acc[mi][ni] = __builtin_amdgcn_mfma_f32_16x16x32_bf16(aL[mi], bH[ni], acc[mi][ni], 0, 0, 0);
            }
        __syncthreads();
    }

    // C (fp16) write
#pragma unroll
    for (int mi = 0; mi < 4; ++mi) {
#pragma unroll
        for (int ni = 0; ni < 4; ++ni) {
            int rbase = mb * 128 + wm * 64 + mi * 16 + (lane >> 4) * 4;
            int c = nb * 128 + wn * 64 + ni * 16 + (lane & 15);
#pragma unroll
            for (int i = 0; i < 4; ++i) {
                int row = rbase + i;
                if (row < M) C[(size_t)row * F512 + c] = __float2half_rn(acc[mi][ni][i]);
            }
        }
    }

    // fused alpha: this wave's 64 cols == head (nb*2+wn)
    int head = nb * 2 + wn;
    float av[4], dv[4];
#pragma unroll
    for (int ni = 0; ni < 4; ++ni) {
        int cw = ni * 16 + (lane & 15);
        av[ni] = asrc2[head * 64 + cw];
        dv[ni] = adst2[head * 64 + cw];
    }
#pragma unroll
    for (int mi = 0; mi < 4; ++mi)
#pragma unroll
        for (int i = 0; i < 4; ++i) {
            float sp = 0.f, dp = 0.f;
#pragma unroll
            for (int ni = 0; ni < 4; ++ni) {
                sp += acc[mi][ni][i] * av[ni];
                dp += acc[mi][ni][i] * dv[ni];
            }
            sp += __shfl_xor(sp, 1); dp += __shfl_xor(dp, 1);
            sp += __shfl_xor(sp, 2); dp += __shfl_xor(dp, 2);
            sp += __shfl_xor(sp, 4); dp += __shfl_xor(dp, 4);
            sp += __shfl_xor(sp, 8); dp += __shfl_xor(dp, 8);
            if ((lane & 15) == 0) {
                int row = mb * 128 + wm * 64 + mi * 16 + (lane >> 4) * 4 + i;
                if (row < M) { a_s[row * 8 + head] = sp; a_d[row * 8 + head] = dp; }
            }
        }
}

// ---------------- CSR build ----------------

__global__ void hist_kernel(const int* __restrict__ dst, int E, int* __restrict__ cnt) {
    int e = blockIdx.x * blockDim.x + threadIdx.x;
    if (e < E) atomicAdd(&cnt[dst[e]], 1);
}

__global__ __launch_bounds__(1024) void scan_block_kernel(const int* __restrict__ cnt,
                                                          int* __restrict__ excl,
                                                          int* __restrict__ bsum, int n) {
    __shared__ int s[1024];
    int i = blockIdx.x * 1024 + threadIdx.x;
    int v = i < n ? cnt[i] : 0;
    s[threadIdx.x] = v;
    __syncthreads();
    for (int off = 1; off < 1024; off <<= 1) {
        int t = threadIdx.x >= off ? s[threadIdx.x - off] : 0;
        __syncthreads();
        s[threadIdx.x] += t;
        __syncthreads();
    }
    if (i < n) excl[i] = s[threadIdx.x] - v;
    if (threadIdx.x == 1023) bsum[blockIdx.x] = s[1023];
}

__global__ void scan_aux_kernel(int* __restrict__ bsum, int nb) {
    if (blockIdx.x == 0 && threadIdx.x == 0) {
        int acc = 0;
        for (int i = 0; i < nb; ++i) { int v = bsum[i]; bsum[i] = acc; acc += v; }
    }
}

__global__ void scan_add_kernel(const int* __restrict__ excl, const int* __restrict__ bsum,
                                int* __restrict__ rowptr, int* __restrict__ fill, int n, int E) {
    int i = blockIdx.x * blockDim.x + threadIdx.x;
    if (i < n) {
        int v = excl[i] + bsum[i >> 10];
        rowptr[i] = v;
        fill[i] = v;
    }
    if (i == 0) rowptr[n] = E;
}

__global__ void scatter_kernel(const int* __restrict__ src, const int* __restrict__ dst, int E,
                               int* __restrict__ fill, int* __restrict__ csrc) {
    int e = blockIdx.x * blockDim.x + threadIdx.x;
    if (e >= E) return;
    int pos = atomicAdd(&fill[dst[e]], 1);
    csrc[pos] = src[e];
}

// ---------------- wave-per-dst fused softmax + aggregation ----------------
// lane l owns channels [8l, 8l+8); head for channels = l>>3; head for alpha
// phases = l&7. One implicit self-loop (index == deg).
// MODE 0: epilogue bias+ELU -> packed split-bf16 (layer-1 out, feeds gemm2)
// MODE 1: epilogue bias+ELU -> h3 = h2@W3, as3/ad3 (layer-2, h2 not stored)

template <int MODE>
__global__ __launch_bounds__(256) void gat_aggr_wave(
    const int* __restrict__ rowptr, const int* __restrict__ csrc,
    const float* __restrict__ a_s, const float* __restrict__ a_d,
    const __half* __restrict__ h16, const float* __restrict__ bias,
    unsigned* __restrict__ outp,
    const float* __restrict__ W3, const float* __restrict__ asrc3,
    const float* __restrict__ adst3, float* __restrict__ h3,
    float* __restrict__ as3, float* __restrict__ ad3, int N) {
    __shared__ float sexs[4][64 * 8];
    __shared__ int ssrcs[4][64];
    int wv = threadIdx.x >> 6, l = threadIdx.x & 63;
    int d = blockIdx.x * 4 + wv;
    if (d >= N) return;
    float* SX = sexs[wv];
    int* SS = ssrcs[wv];
    int beg = rowptr[d], deg = rowptr[d + 1] - beg;
    int hq = l & 7, hmy = l >> 3;
    float adq = a_d[d * 8 + hq];

    // pass 1: per-head max over all edges (+self)
    float m = -INFINITY;
    for (int i = l >> 3; i <= deg; i += 8) {
        int s = (i == deg) ? d : csrc[beg + i];
        float v = a_s[s * 8 + hq] + adq;
        v = v >= 0.f ? v : 0.2f * v;
        m = fmaxf(m, v);
    }
    m = fmaxf(m, __shfl_xor(m, 8));
    m = fmaxf(m, __shfl_xor(m, 16));
    m = fmaxf(m, __shfl_xor(m, 32));

    // pass 2 (chunked): exp -> LDS, denom partial, feature accumulate
    float den = 0.f;
    float acc[8] = {};
    for (int c0 = 0; c0 <= deg; c0 += 64) {
        int cnt = min(64, deg + 1 - c0);
        if (l < cnt) {
            int i = c0 + l;
            SS[l] = (i == deg) ? d : csrc[beg + i];
        }
        __builtin_amdgcn_wave_barrier();
        for (int i = l >> 3; i < cnt; i += 8) {
            int s = SS[i];
            float v = a_s[s * 8 + hq] + adq;
            v = v >= 0.f ? v : 0.2f * v;
            float ex = __expf(v - m);
            SX[i * 8 + hq] = ex;
            den += ex;
        }
        __builtin_amdgcn_wave_barrier();
        for (int j = 0; j < cnt; ++j) {
            int s = SS[j];
            float ex = SX[j * 8 + hmy];
            uint4 hv = *(const uint4*)(h16 + (size_t)s * F512 + l * 8);
            const __half2* hp = (const __half2*)&hv;
#pragma unroll
            for (int k = 0; k < 4; ++k) {
                float2 f = __half22float2(hp[k]);
                acc[2 * k] += ex * f.x;
                acc[2 * k + 1] += ex * f.y;
            }
        }
        __builtin_amdgcn_wave_barrier();
    }
    den += __shfl_xor(den, 8);
    den += __shfl_xor(den, 16);
    den += __shfl_xor(den, 32);
    float dg = __shfl(den, hmy);
    float inv = 1.f / (dg + 1e-16f);

    int c0c = l * 8;
    float o[8];
#pragma unroll
    for (int k = 0; k < 8; ++k) {
        float t = acc[k] * inv + bias[c0c + k];
        o[k] = t > 0.f ? t : expm1f(t);
    }

    if (MODE == 0) {
        unsigned pk[8];
#pragma unroll
        for (int k = 0; k < 8; ++k) pk[k] = pack_split(o[k]);
        uint4* op = (uint4*)(outp + (size_t)d * F512 + c0c);
        op[0] = *(uint4*)&pk[0];
        op[1] = *(uint4*)&pk[4];
    } else {
        float p0 = 0.f, p1 = 0.f, p2 = 0.f;
#pragma unroll
        for (int k = 0; k < 8; ++k) {
            float t = o[k];
            p0 += t * W3[(c0c + k) * 3 + 0];
            p1 += t * W3[(c0c + k) * 3 + 1];
            p2 += t * W3[(c0c + k) * 3 + 2];
        }
#pragma unroll
        for (int off = 1; off < 64; off <<= 1) {
            p0 += __shfl_xor(p0, off);
            p1 += __shfl_xor(p1, off);
            p2 += __shfl_xor(p2, off);
        }
        if (l == 0) {
            h3[(size_t)d * 3 + 0] = p0;
            h3[(size_t)d * 3 + 1] = p1;
            h3[(size_t)d * 3 + 2] = p2;
            as3[d] = p0 * asrc3[0] + p1 * asrc3[1] + p2 * asrc3[2];
            ad3[d] = p0 * adst3[0] + p1 * adst3[1] + p2 * adst3[2];
        }
    }
}

// Layer 3: wave per destination node, 3 channels, single head. No ELU.
__global__ __launch_bounds__(256) void gat_aggr3_fused(
    const int* __restrict__ rowptr, const int* __restrict__ csrc,
    const float* __restrict__ a_s, const float* __restrict__ a_d,
    const float* __restrict__ h3, const float* __restrict__ b3,
    float* __restrict__ out, int N) {
    int w = (blockIdx.x * blockDim.x + threadIdx.x) >> 6;
    int lane = threadIdx.x & 63;
    if (w >= N) return;
    int d = w;
    int beg = rowptr[d], deg = rowptr[d + 1] - beg;
    float ad = a_d[d];
    float m = -INFINITY;
    for (int i = lane; i <= deg; i += 64) {
        int s = (i == deg) ? d : csrc[beg + i];
        float v = a_s[s] + ad;
        v = v >= 0.f ? v : 0.2f * v;
        m = fmaxf(m, v);
    }
    for (int off = 32; off; off >>= 1) m = fmaxf(m, __shfl_xor(m, off));
    float den = 0.f, c0 = 0.f, c1 = 0.f, c2 = 0.f;
    for (int i = lane; i <= deg; i += 64) {
        int s = (i == deg) ? d : csrc[beg + i];
        float v = a_s[s] + ad;
        v = v >= 0.f ? v : 0.2f * v;
        float ex = __expf(v - m);
        den += ex;
        c0 += ex * h3[(size_t)s * 3 + 0];
        c1 += ex * h3[(size_t)s * 3 + 1];
        c2 += ex * h3[(size_t)s * 3 + 2];
    }
    for (int off = 32; off; off >>= 1) {
        den += __shfl_xor(den, off);
        c0 += __shfl_xor(c0, off);
        c1 += __shfl_xor(c1, off);
        c2 += __shfl_xor(c2, off);
    }
    if (lane == 0) {
        float inv = 1.f / (den + 1e-16f);
        out[(size_t)d * 3 + 0] = c0 * inv + b3[0];
        out[(size_t)d * 3 + 1] = c1 * inv + b3[1];
        out[(size_t)d * 3 + 2] = c2 * inv + b3[2];
    }
}

static inline int cdiv(long long a, long long b) { return (int)((a + b - 1) / b); }
static inline size_t rup(size_t v) { return (v + 255) & ~(size_t)255; }

extern "C" void kernel_launch(void* const* d_in, const int* in_sizes, int n_in,
                              void* d_out, int out_size, void* d_ws, size_t ws_size,
                              hipStream_t stream) {
    const int N = in_sizes[0] / 12;
    const int E = in_sizes[1] / 2;
    const float* x     = (const float*)d_in[0];
    const int*   ei    = (const int*)d_in[1];
    const float* W1    = (const float*)d_in[2];
    const float* asrc1 = (const float*)d_in[3];
    const float* adst1 = (const float*)d_in[4];
    const float* b1    = (const float*)d_in[5];
    const float* W2    = (const float*)d_in[6];
    const float* asrc2 = (const float*)d_in[7];
    const float* adst2 = (const float*)d_in[8];
    const float* b2    = (const float*)d_in[9];
    const float* W3    = (const float*)d_in[10];
    const float* asrc3 = (const float*)d_in[11];
    const float* adst3 = (const float*)d_in[12];
    const float* b3    = (const float*)d_in[13];

    const int* srcv = ei;
    const int* dstv = ei + E;
    float* out = (float*)d_out;

    const int Mpad = cdiv(N, 128) * 128;
    char* ws = (char*)d_ws;
    size_t szH16 = rup((size_t)Mpad * F512 * 2);     // fp16 features
    size_t szHp  = rup((size_t)Mpad * F512 * 4);     // packed split-bf16
    __half*   h16 = (__half*)ws;
    unsigned* hBp = (unsigned*)(ws + szH16);
    char* p = ws + szH16 + szHp;
    float* a_s    = (float*)p;  p += rup((size_t)Mpad * HEADS * 4);
    float* a_d    = (float*)p;  p += rup((size_t)Mpad * HEADS * 4);
    float* h3     = (float*)p;  p += rup((size_t)N * 3 * 4);
    float* as3    = (float*)p;  p += rup((size_t)N * 4);
    float* ad3    = (float*)p;  p += rup((size_t)N * 4);
    int*   cnt    = (int*)p;    p += rup((size_t)N * 4);
    int*   excl   = (int*)p;    p += rup((size_t)N * 4);
    int*   rowptr = (int*)p;    p += rup((size_t)(N + 1) * 4);
    int*   fill   = (int*)p;    p += rup((size_t)N * 4);
    int*   bsum   = (int*)p;    p += rup(4096);
    int*   csrc   = (int*)p;    p += rup((size_t)E * 4);
    unsigned* BT  = (unsigned*)p;  // 512*512 packed = 1 MB

    const int nb = cdiv(N, 1024);

    // ---- CSR build (shared by all 3 layers) + W2 split-convert ----
    hipMemsetAsync(cnt, 0, (size_t)N * 4, stream);
    hist_kernel<<<cdiv(E, 256), 256, 0, stream>>>(dstv, E, cnt);
    scan_block_kernel<<<nb, 1024, 0, stream>>>(cnt, excl, bsum, N);
    scan_aux_kernel<<<1, 64, 0, stream>>>(bsum, nb);
    scan_add_kernel<<<cdiv(N + 1, 256), 256, 0, stream>>>(excl, bsum, rowptr, fill, N, E);
    scatter_kernel<<<cdiv(E, 256), 256, 0, stream>>>(srcv, dstv, E, fill, csrc);
    convW2_kernel<<<cdiv((long long)F512 * F512, 256), 256, 0, stream>>>(W2, BT);

    // ----------------- Layer 1 -----------------
    gemm1_fused<<<cdiv((long long)N * 64, 256), 256, 0, stream>>>(
        x, W1, asrc1, adst1, h16, a_s, a_d, N);
    gat_aggr_wave<0><<<cdiv(N, 4), 256, 0, stream>>>(
        rowptr, csrc, a_s, a_d, h16, b1, hBp,
        nullptr, nullptr, nullptr, nullptr, nullptr, nullptr, N);

    // ----------------- Layer 2 -----------------
    gemm2_mfma<<<(Mpad / 128) * 4, 256, 0, stream>>>(
        hBp, BT, asrc2, adst2, h16, a_s, a_d, N);
    gat_aggr_wave<1><<<cdiv(N, 4), 256, 0, stream>>>(
        rowptr, csrc, a_s, a_d, h16, b2, nullptr,
        W3, asrc3, adst3, h3, as3, ad3, N);

    // ----------------- Layer 3 -----------------
    gat_aggr3_fused<<<cdiv((long long)N, 4), 256, 0, stream>>>(
        rowptr, csrc, as3, ad3, h3, b3, out, N);
}

// Round 9
// 502.087 us; speedup vs baseline: 6.1795x; 1.0190x over previous
//
#include <hip/hip_runtime.h>
#include <hip/hip_bf16.h>
#include <hip/hip_fp16.h>

// ---------------------------------------------------------------------------
// GAT 3-layer forward, round 9 = round-5 architecture (known-pass) + the
// empirically-exonerated GEMM2 operand pipeline (separate hi/lo bf16 planes,
// chunk-swizzled in global, staged via global_load_lds width=16).
//  - wave-per-dst aggregation; alphas fused into gemm1/gemm2 epilogues
//  - layer-2 output never materialized (h3 computed in aggregation epilogue)
//  - layer-2 GEMM: split-bf16 MFMA (Ah*Bh + Ah*Bl + Al*Bh), f32-quality
// ---------------------------------------------------------------------------

#define HEADS 8
#define F512 512

typedef __bf16 bf16x8 __attribute__((ext_vector_type(8)));
typedef unsigned short u16x8 __attribute__((ext_vector_type(8)));
typedef float f32x4 __attribute__((ext_vector_type(4)));

__device__ __forceinline__ unsigned bf16_rne(float f) {
    unsigned u = __float_as_uint(f);
    return (u + 0x7FFFu + ((u >> 16) & 1u)) >> 16;
}

#if defined(__has_builtin)
#if __has_builtin(__builtin_amdgcn_global_load_lds)
#define HAS_GLL 1
#endif
#endif

__device__ __forceinline__ void gll16(const void* g, void* l) {
#ifdef HAS_GLL
    __builtin_amdgcn_global_load_lds(
        (const __attribute__((address_space(1))) unsigned int*)g,
        (__attribute__((address_space(3))) unsigned int*)l, 16, 0, 0);
#else
    *(uint4*)l = *(const uint4*)g;
#endif
}

// ---------------- Layer-1 GEMM + alpha, wave per node (round-5) ----------------
__global__ __launch_bounds__(256) void gemm1_fused(
    const float* __restrict__ x, const float* __restrict__ W1,
    const float* __restrict__ asrc, const float* __restrict__ adst,
    __half* __restrict__ h16, float* __restrict__ a_s, float* __restrict__ a_d,
    int N) {
    int w = (blockIdx.x * blockDim.x + threadIdx.x) >> 6;
    int l = threadIdx.x & 63;
    if (w >= N) return;
    const float* xr = x + (size_t)w * 12;
    float4 xa = *(const float4*)(xr);
    float4 xb = *(const float4*)(xr + 4);
    float4 xc = *(const float4*)(xr + 8);
    float xv[12] = {xa.x, xa.y, xa.z, xa.w, xb.x, xb.y, xb.z, xb.w, xc.x, xc.y, xc.z, xc.w};
    int c0 = l * 8;
    float o[8] = {};
#pragma unroll
    for (int k = 0; k < 12; ++k) {
        const float4* wr = (const float4*)(W1 + k * F512 + c0);
        float4 w0 = wr[0], w1 = wr[1];
        o[0] += xv[k] * w0.x; o[1] += xv[k] * w0.y; o[2] += xv[k] * w0.z; o[3] += xv[k] * w0.w;
        o[4] += xv[k] * w1.x; o[5] += xv[k] * w1.y; o[6] += xv[k] * w1.z; o[7] += xv[k] * w1.w;
    }
    __half hv[8];
#pragma unroll
    for (int k = 0; k < 8; ++k) hv[k] = __float2half_rn(o[k]);
    *(uint4*)(h16 + (size_t)w * F512 + c0) = *(uint4*)hv;
    float s = 0.f, d = 0.f;
#pragma unroll
    for (int k = 0; k < 8; ++k) { s += o[k] * asrc[c0 + k]; d += o[k] * adst[c0 + k]; }
    s += __shfl_xor(s, 1); d += __shfl_xor(d, 1);
    s += __shfl_xor(s, 2); d += __shfl_xor(d, 2);
    s += __shfl_xor(s, 4); d += __shfl_xor(d, 4);
    if ((l & 7) == 0) { a_s[w * 8 + (l >> 3)] = s; a_d[w * 8 + (l >> 3)] = d; }
}

// W2 [K=512][N=512] -> chunk-swizzled bf16 hi/lo planes, n-major [n][k]
__global__ void convW2p(const float* __restrict__ W2, unsigned short* __restrict__ BTH,
                        unsigned short* __restrict__ BTL) {
    int t = blockIdx.x * blockDim.x + threadIdx.x;
    if (t >= F512 * 64) return;
    int n = t >> 6, c = t & 63;                 // c = logical 8-elem chunk of k
    int g = c >> 2, cc = c & 3;
    int st = g * 32 + ((cc ^ ((n >> 1) & 3)) << 3);
    unsigned short hs[8], ls[8];
#pragma unroll
    for (int j = 0; j < 8; ++j) {
        float f = W2[(size_t)(c * 8 + j) * F512 + n];
        unsigned hi = bf16_rne(f);
        float r = f - __uint_as_float(hi << 16);
        hs[j] = (unsigned short)hi;
        ls[j] = (unsigned short)bf16_rne(r);
    }
    *(uint4*)&BTH[(size_t)n * F512 + st] = *(uint4*)hs;
    *(uint4*)&BTL[(size_t)n * F512 + st] = *(uint4*)ls;
}

// ---------------- CSR build ----------------

__global__ void hist_kernel(const int* __restrict__ dst, int E, int* __restrict__ cnt) {
    int e = blockIdx.x * blockDim.x + threadIdx.x;
    if (e < E) atomicAdd(&cnt[dst[e]], 1);
}

__global__ __launch_bounds__(1024) void scan_block_kernel(const int* __restrict__ cnt,
                                                          int* __restrict__ excl,
                                                          int* __restrict__ bsum, int n) {
    __shared__ int s[1024];
    int i = blockIdx.x * 1024 + threadIdx.x;
    int v = i < n ? cnt[i] : 0;
    s[threadIdx.x] = v;
    __syncthreads();
    for (int off = 1; off < 1024; off <<= 1) {
        int t = threadIdx.x >= off ? s[threadIdx.x - off] : 0;
        __syncthreads();
        s[threadIdx.x] += t;
        __syncthreads();
    }
    if (i < n) excl[i] = s[threadIdx.x] - v;
    if (threadIdx.x == 1023) bsum[blockIdx.x] = s[1023];
}

__global__ void scan_aux_kernel(int* __restrict__ bsum, int nb) {
    if (blockIdx.x == 0 && threadIdx.x == 0) {
        int acc = 0;
        for (int i = 0; i < nb; ++i) { int v = bsum[i]; bsum[i] = acc; acc += v; }
    }
}

__global__ void scan_add_kernel(const int* __restrict__ excl, const int* __restrict__ bsum,
                                int* __restrict__ rowptr, int* __restrict__ fill, int n, int E) {
    int i = blockIdx.x * blockDim.x + threadIdx.x;
    if (i < n) {
        int v = excl[i] + bsum[i >> 10];
        rowptr[i] = v;
        fill[i] = v;
    }
    if (i == 0) rowptr[n] = E;
}

__global__ void scatter_kernel(const int* __restrict__ src, const int* __restrict__ dst, int E,
                               int* __restrict__ fill, int* __restrict__ csrc) {
    int e = blockIdx.x * blockDim.x + threadIdx.x;
    if (e >= E) return;
    int pos = atomicAdd(&fill[dst[e]], 1);
    csrc[pos] = src[e];
}

// ---------------- wave-per-dst fused softmax + aggregation (round-5) ----------------
// MODE 0: epilogue bias+ELU -> hi/lo bf16 planes, chunk-swizzled (feeds gemm2)
// MODE 1: epilogue bias+ELU -> h3 = h2@W3, as3/ad3 (h2 not stored)

template <int MODE>
__global__ __launch_bounds__(256) void gat_aggr_wave(
    const int* __restrict__ rowptr, const int* __restrict__ csrc,
    const float* __restrict__ a_s, const float* __restrict__ a_d,
    const __half* __restrict__ h16, const float* __restrict__ bias,
    unsigned short* __restrict__ aggH, unsigned short* __restrict__ aggL,
    const float* __restrict__ W3, const float* __restrict__ asrc3,
    const float* __restrict__ adst3, float* __restrict__ h3,
    float* __restrict__ as3, float* __restrict__ ad3, int N) {
    __shared__ float sexs[4][64 * 8];
    __shared__ int ssrcs[4][64];
    int wv = threadIdx.x >> 6, l = threadIdx.x & 63;
    int d = blockIdx.x * 4 + wv;
    if (d >= N) return;
    float* SX = sexs[wv];
    int* SS = ssrcs[wv];
    int beg = rowptr[d], deg = rowptr[d + 1] - beg;
    int hq = l & 7, hmy = l >> 3;
    float adq = a_d[d * 8 + hq];

    float m = -INFINITY;
    for (int i = l >> 3; i <= deg; i += 8) {
        int s = (i == deg) ? d : csrc[beg + i];
        float v = a_s[s * 8 + hq] + adq;
        v = v >= 0.f ? v : 0.2f * v;
        m = fmaxf(m, v);
    }
    m = fmaxf(m, __shfl_xor(m, 8));
    m = fmaxf(m, __shfl_xor(m, 16));
    m = fmaxf(m, __shfl_xor(m, 32));

    float den = 0.f;
    float acc[8] = {};
    for (int c0 = 0; c0 <= deg; c0 += 64) {
        int cnt = min(64, deg + 1 - c0);
        if (l < cnt) {
            int i = c0 + l;
            SS[l] = (i == deg) ? d : csrc[beg + i];
        }
        __builtin_amdgcn_wave_barrier();
        for (int i = l >> 3; i < cnt; i += 8) {
            int s = SS[i];
            float v = a_s[s * 8 + hq] + adq;
            v = v >= 0.f ? v : 0.2f * v;
            float ex = __expf(v - m);
            SX[i * 8 + hq] = ex;
            den += ex;
        }
        __builtin_amdgcn_wave_barrier();
        for (int j = 0; j < cnt; ++j) {
            int s = SS[j];
            float ex = SX[j * 8 + hmy];
            uint4 hv = *(const uint4*)(h16 + (size_t)s * F512 + l * 8);
            const __half2* hp = (const __half2*)&hv;
#pragma unroll
            for (int k = 0; k < 4; ++k) {
                float2 f = __half22float2(hp[k]);
                acc[2 * k] += ex * f.x;
                acc[2 * k + 1] += ex * f.y;
            }
        }
        __builtin_amdgcn_wave_barrier();
    }
    den += __shfl_xor(den, 8);
    den += __shfl_xor(den, 16);
    den += __shfl_xor(den, 32);
    float dg = __shfl(den, hmy);
    float inv = 1.f / (dg + 1e-16f);

    int c0c = l * 8;
    float o[8];
#pragma unroll
    for (int k = 0; k < 8; ++k) {
        float t = acc[k] * inv + bias[c0c + k];
        o[k] = t > 0.f ? t : expm1f(t);
    }

    if (MODE == 0) {
        unsigned short hs[8], ls[8];
#pragma unroll
        for (int k = 0; k < 8; ++k) {
            unsigned hi = bf16_rne(o[k]);
            float r = o[k] - __uint_as_float(hi << 16);
            hs[k] = (unsigned short)hi;
            ls[k] = (unsigned short)bf16_rne(r);
        }
        // logical chunk l -> swizzled slot (pre-swizzled global layout)
        int st = (l >> 2) * 32 + (((l & 3) ^ ((d >> 1) & 3)) << 3);
        *(uint4*)&aggH[(size_t)d * F512 + st] = *(uint4*)hs;
        *(uint4*)&aggL[(size_t)d * F512 + st] = *(uint4*)ls;
    } else {
        float p0 = 0.f, p1 = 0.f, p2 = 0.f;
#pragma unroll
        for (int k = 0; k < 8; ++k) {
            float t = o[k];
            p0 += t * W3[(c0c + k) * 3 + 0];
            p1 += t * W3[(c0c + k) * 3 + 1];
            p2 += t * W3[(c0c + k) * 3 + 2];
        }
#pragma unroll
        for (int off = 1; off < 64; off <<= 1) {
            p0 += __shfl_xor(p0, off);
            p1 += __shfl_xor(p1, off);
            p2 += __shfl_xor(p2, off);
        }
        if (l == 0) {
            h3[(size_t)d * 3 + 0] = p0;
            h3[(size_t)d * 3 + 1] = p1;
            h3[(size_t)d * 3 + 2] = p2;
            as3[d] = p0 * asrc3[0] + p1 * asrc3[1] + p2 * asrc3[2];
            ad3[d] = p0 * adst3[0] + p1 * adst3[1] + p2 * adst3[2];
        }
    }
}

// ---------------- Layer-2 GEMM: hi/lo planes + global_load_lds + fused alpha ----------------
// C = h1 @ W2 (pre-bias) -> h2pre fp16; alphas2 from f32 acc. 128x128, BK=32.
__global__ __launch_bounds__(256) void gemm2_gll(
    const unsigned short* __restrict__ AH, const unsigned short* __restrict__ AL,
    const unsigned short* __restrict__ BH, const unsigned short* __restrict__ BL,
    const float* __restrict__ asrc2, const float* __restrict__ adst2,
    __half* __restrict__ C, float* __restrict__ a_s, float* __restrict__ a_d,
    int M) {
    __shared__ unsigned short AsH[128 * 32], AsL[128 * 32];
    __shared__ unsigned short BsH[128 * 32], BsL[128 * 32];

    int nwg = gridDim.x, o = blockIdx.x;
    int q = nwg >> 3, r = nwg & 7, xcd = o & 7;
    int base = xcd < r ? xcd * (q + 1) : r * (q + 1) + (xcd - r) * q;
    int lg = base + (o >> 3);
    int mb = lg >> 2, nb = lg & 3;

    int tid = threadIdx.x, lane = tid & 63, wv = tid >> 6;
    int wm = wv >> 1, wn = wv & 1;
    int seg = lane >> 4;
    int srow = tid >> 2, sch = tid & 3;

    f32x4 acc[4][4] = {};

    for (int k0 = 0; k0 < F512; k0 += 32) {
#pragma unroll
        for (int u = 0; u < 2; ++u) {
            size_t ga = (size_t)(mb * 128 + srow + u * 64) * F512 + k0 + sch * 8;
            size_t gb = (size_t)(nb * 128 + srow + u * 64) * F512 + k0 + sch * 8;
            int ldst = wv * 512 + u * 2048;
            gll16(AH + ga, &AsH[ldst]);
            gll16(AL + ga, &AsL[ldst]);
            gll16(BH + gb, &BsH[ldst]);
            gll16(BL + gb, &BsL[ldst]);
        }
        __syncthreads();

        bf16x8 aH[4], aL[4], bH[4], bL[4];
#pragma unroll
        for (int mi = 0; mi < 4; ++mi) {
            int arow = wm * 64 + mi * 16 + (lane & 15);
            int aoff = arow * 32 + ((seg ^ ((arow >> 1) & 3)) << 3);
            aH[mi] = __builtin_bit_cast(bf16x8, *(const u16x8*)&AsH[aoff]);
            aL[mi] = __builtin_bit_cast(bf16x8, *(const u16x8*)&AsL[aoff]);
        }
#pragma unroll
        for (int ni = 0; ni < 4; ++ni) {
            int brow = wn * 64 + ni * 16 + (lane & 15);
            int boff = brow * 32 + ((seg ^ ((brow >> 1) & 3)) << 3);
            bH[ni] = __builtin_bit_cast(bf16x8, *(const u16x8*)&BsH[boff]);
            bL[ni] = __builtin_bit_cast(bf16x8, *(const u16x8*)&BsL[boff]);
        }
#pragma unroll
        for (int mi = 0; mi < 4; ++mi)
#pragma unroll
            for (int ni = 0; ni < 4; ++ni) {
                acc[mi][ni] = __builtin_amdgcn_mfma_f32_16x16x32_bf16(aH[mi], bH[ni], acc[mi][ni], 0, 0, 0);
                acc[mi][ni] = __builtin_amdgcn_mfma_f32_16x16x32_bf16(aH[mi], bL[ni], acc[mi][ni], 0, 0, 0);
                acc[mi][ni] = __builtin_amdgcn_mfma_f32_16x16x32_bf16(aL[mi], bH[ni], acc[mi][ni], 0, 0, 0);
            }
        __syncthreads();
    }

    // C (fp16 h2pre) write
#pragma unroll
    for (int mi = 0; mi < 4; ++mi) {
#pragma unroll
        for (int ni = 0; ni < 4; ++ni) {
            int rbase = mb * 128 + wm * 64 + mi * 16 + (lane >> 4) * 4;
            int c = nb * 128 + wn * 64 + ni * 16 + (lane & 15);
#pragma unroll
            for (int i = 0; i < 4; ++i) {
                int row = rbase + i;
                if (row < M) C[(size_t)row * F512 + c] = __float2half_rn(acc[mi][ni][i]);
            }
        }
    }

    // fused alpha: this wave's 64 cols == head (nb*2+wn)
    int head = nb * 2 + wn;
    float av[4], dv[4];
#pragma unroll
    for (int ni = 0; ni < 4; ++ni) {
        int cw = ni * 16 + (lane & 15);
        av[ni] = asrc2[head * 64 + cw];
        dv[ni] = adst2[head * 64 + cw];
    }
#pragma unroll
    for (int mi = 0; mi < 4; ++mi)
#pragma unroll
        for (int i = 0; i < 4; ++i) {
            float sp = 0.f, dp = 0.f;
#pragma unroll
            for (int ni = 0; ni < 4; ++ni) {
                sp += acc[mi][ni][i] * av[ni];
                dp += acc[mi][ni][i] * dv[ni];
            }
            sp += __shfl_xor(sp, 1); dp += __shfl_xor(dp, 1);
            sp += __shfl_xor(sp, 2); dp += __shfl_xor(dp, 2);
            sp += __shfl_xor(sp, 4); dp += __shfl_xor(dp, 4);
            sp += __shfl_xor(sp, 8); dp += __shfl_xor(dp, 8);
            if ((lane & 15) == 0) {
                int row = mb * 128 + wm * 64 + mi * 16 + (lane >> 4) * 4 + i;
                if (row < M) { a_s[row * 8 + head] = sp; a_d[row * 8 + head] = dp; }
            }
        }
}

// ---------------- layer-3 aggregation ----------------
__global__ __launch_bounds__(256) void gat_aggr3_fused(
    const int* __restrict__ rowptr, const int* __restrict__ csrc,
    const float* __restrict__ a_s, const float* __restrict__ a_d,
    const float* __restrict__ h3, const float* __restrict__ b3,
    float* __restrict__ out, int N) {
    int w = (blockIdx.x * blockDim.x + threadIdx.x) >> 6;
    int lane = threadIdx.x & 63;
    if (w >= N) return;
    int d = w;
    int beg = rowptr[d], deg = rowptr[d + 1] - beg;
    float ad = a_d[d];
    float m = -INFINITY;
    for (int i = lane; i <= deg; i += 64) {
        int s = (i == deg) ? d : csrc[beg + i];
        float v = a_s[s] + ad;
        v = v >= 0.f ? v : 0.2f * v;
        m = fmaxf(m, v);
    }
    for (int off = 32; off; off >>= 1) m = fmaxf(m, __shfl_xor(m, off));
    float den = 0.f, c0 = 0.f, c1 = 0.f, c2 = 0.f;
    for (int i = lane; i <= deg; i += 64) {
        int s = (i == deg) ? d : csrc[beg + i];
        float v = a_s[s] + ad;
        v = v >= 0.f ? v : 0.2f * v;
        float ex = __expf(v - m);
        den += ex;
        c0 += ex * h3[(size_t)s * 3 + 0];
        c1 += ex * h3[(size_t)s * 3 + 1];
        c2 += ex * h3[(size_t)s * 3 + 2];
    }
    for (int off = 32; off; off >>= 1) {
        den += __shfl_xor(den, off);
        c0 += __shfl_xor(c0, off);
        c1 += __shfl_xor(c1, off);
        c2 += __shfl_xor(c2, off);
    }
    if (lane == 0) {
        float inv = 1.f / (den + 1e-16f);
        out[(size_t)d * 3 + 0] = c0 * inv + b3[0];
        out[(size_t)d * 3 + 1] = c1 * inv + b3[1];
        out[(size_t)d * 3 + 2] = c2 * inv + b3[2];
    }
}

static inline int cdiv(long long a, long long b) { return (int)((a + b - 1) / b); }
static inline size_t rup(size_t v) { return (v + 255) & ~(size_t)255; }

extern "C" void kernel_launch(void* const* d_in, const int* in_sizes, int n_in,
                              void* d_out, int out_size, void* d_ws, size_t ws_size,
                              hipStream_t stream) {
    const int N = in_sizes[0] / 12;
    const int E = in_sizes[1] / 2;
    const float* x     = (const float*)d_in[0];
    const int*   ei    = (const int*)d_in[1];
    const float* W1    = (const float*)d_in[2];
    const float* asrc1 = (const float*)d_in[3];
    const float* adst1 = (const float*)d_in[4];
    const float* b1    = (const float*)d_in[5];
    const float* W2    = (const float*)d_in[6];
    const float* asrc2 = (const float*)d_in[7];
    const float* adst2 = (const float*)d_in[8];
    const float* b2    = (const float*)d_in[9];
    const float* W3    = (const float*)d_in[10];
    const float* asrc3 = (const float*)d_in[11];
    const float* adst3 = (const float*)d_in[12];
    const float* b3    = (const float*)d_in[13];

    const int* srcv = ei;
    const int* dstv = ei + E;
    float* out = (float*)d_out;

    const int Mpad = cdiv(N, 128) * 128;
    char* p = (char*)d_ws;
    __half*         h16  = (__half*)p;         p += rup((size_t)N * F512 * 2);
    unsigned short* aggH = (unsigned short*)p; p += rup((size_t)Mpad * F512 * 2);
    unsigned short* aggL = (unsigned short*)p; p += rup((size_t)Mpad * F512 * 2);
    float* a_s    = (float*)p;  p += rup((size_t)Mpad * HEADS * 4);
    float* a_d    = (float*)p;  p += rup((size_t)Mpad * HEADS * 4);
    float* h3     = (float*)p;  p += rup((size_t)N * 3 * 4);
    float* as3    = (float*)p;  p += rup((size_t)N * 4);
    float* ad3    = (float*)p;  p += rup((size_t)N * 4);
    int*   cnt    = (int*)p;    p += rup((size_t)N * 4);
    int*   excl   = (int*)p;    p += rup((size_t)N * 4);
    int*   rowptr = (int*)p;    p += rup((size_t)(N + 1) * 4);
    int*   fill   = (int*)p;    p += rup((size_t)N * 4);
    int*   bsum   = (int*)p;    p += rup(4096);
    int*   csrc   = (int*)p;    p += rup((size_t)E * 4);
    unsigned short* BTH = (unsigned short*)p; p += rup((size_t)F512 * F512 * 2);
    unsigned short* BTL = (unsigned short*)p; p += rup((size_t)F512 * F512 * 2);

    const int nb = cdiv(N, 1024);

    // ---- CSR build + W2 plane conversion ----
    hipMemsetAsync(cnt, 0, (size_t)N * 4, stream);
    hist_kernel<<<cdiv(E, 256), 256, 0, stream>>>(dstv, E, cnt);
    scan_block_kernel<<<nb, 1024, 0, stream>>>(cnt, excl, bsum, N);
    scan_aux_kernel<<<1, 64, 0, stream>>>(bsum, nb);
    scan_add_kernel<<<cdiv(N + 1, 256), 256, 0, stream>>>(excl, bsum, rowptr, fill, N, E);
    scatter_kernel<<<cdiv(E, 256), 256, 0, stream>>>(srcv, dstv, E, fill, csrc);
    convW2p<<<cdiv(F512 * 64, 256), 256, 0, stream>>>(W2, BTH, BTL);

    // ----------------- Layer 1 -----------------
    gemm1_fused<<<cdiv((long long)N * 64, 256), 256, 0, stream>>>(
        x, W1, asrc1, adst1, h16, a_s, a_d, N);
    gat_aggr_wave<0><<<cdiv(N, 4), 256, 0, stream>>>(
        rowptr, csrc, a_s, a_d, h16, b1, aggH, aggL,
        nullptr, nullptr, nullptr, nullptr, nullptr, nullptr, N);

    // ----------------- Layer 2 -----------------
    gemm2_gll<<<(Mpad / 128) * 4, 256, 0, stream>>>(
        aggH, aggL, BTH, BTL, asrc2, adst2, h16, a_s, a_d, N);
    gat_aggr_wave<1><<<cdiv(N, 4), 256, 0, stream>>>(
        rowptr, csrc, a_s, a_d, h16, b2, nullptr, nullptr,
        W3, asrc3, adst3, h3, as3, ad3, N);

    // ----------------- Layer 3 -----------------
    gat_aggr3_fused<<<cdiv((long long)N, 4), 256, 0, stream>>>(
        rowptr, csrc, as3, ad3, h3, b3, out, N);
}